// Round 6
// baseline (138.037 us; speedup 1.0000x reference)
//
#include <hip/hip_runtime.h>
#include <hip/hip_bf16.h>
#include <stdint.h>

typedef __bf16 bf16_t;
typedef __bf16 bf16x8 __attribute__((ext_vector_type(8)));
typedef __bf16 bf16x4 __attribute__((ext_vector_type(4)));
typedef float  f32x4  __attribute__((ext_vector_type(4)));

#define DEV __device__ __forceinline__

static constexpr int NTOK = 2048;
static constexpr int DIM  = 1024;
static constexpr int NH   = 16;
static constexpr int DH   = 64;
static constexpr int QKVN = 3072;
static constexpr int SLOTS_PER_HEAD = 40;   // sum over Q=0..15 of ceil((Q+1)/4)
static constexpr int PART_STRIDE = 17408;   // 128x64 bf16 (16384) + m2[128] f32 + l[128] f32
static constexpr float L2E = 1.44269504f;

DEV void gload_lds16(const void* g, void* l) {
  __builtin_amdgcn_global_load_lds(
      (__attribute__((address_space(1))) void*)(g),
      (__attribute__((address_space(3))) void*)(l), 16, 0, 0);
}

DEV float bf2f(bf16_t b) { return (float)b; }

// ---------------- fused: LayerNorm (blocks 0..2047) + w_qkv transpose-cast (2048..2815) ----
__global__ __launch_bounds__(256) void k_ln_tc(const float* __restrict__ x,
                                               const float* __restrict__ gamma,
                                               const float* __restrict__ beta,
                                               bf16_t* __restrict__ xn,
                                               const float* __restrict__ wsrc,
                                               bf16_t* __restrict__ wdst) {
  __shared__ float tile[64][65];
  __shared__ float red[8];
  int b = blockIdx.x;
  if (b < NTOK) {
    const int row = b;
    const int t = threadIdx.x;
    const float4* x4 = reinterpret_cast<const float4*>(x);
    float4 v = x4[(size_t)row * 256 + t];
    float s  = v.x + v.y + v.z + v.w;
    float s2 = v.x * v.x + v.y * v.y + v.z * v.z + v.w * v.w;
#pragma unroll
    for (int o = 1; o < 64; o <<= 1) {
      s  += __shfl_xor(s, o, 64);
      s2 += __shfl_xor(s2, o, 64);
    }
    const int w = t >> 6, lane = t & 63;
    if (lane == 0) { red[w] = s; red[4 + w] = s2; }
    __syncthreads();
    s  = red[0] + red[1] + red[2] + red[3];
    s2 = red[4] + red[5] + red[6] + red[7];
    const float mu  = s * (1.0f / 1024.0f);
    const float var = s2 * (1.0f / 1024.0f) - mu * mu;
    const float inv = rsqrtf(var + 1e-6f);
    const float4 g = reinterpret_cast<const float4*>(gamma)[t];
    const float4 bb = reinterpret_cast<const float4*>(beta)[t];
    bf16x4 o;
    o[0] = (bf16_t)((v.x - mu) * inv * g.x + bb.x);
    o[1] = (bf16_t)((v.y - mu) * inv * g.y + bb.y);
    o[2] = (bf16_t)((v.z - mu) * inv * g.z + bb.z);
    o[3] = (bf16_t)((v.w - mu) * inv * g.w + bb.w);
    *reinterpret_cast<bf16x4*>(xn + (size_t)row * DIM + t * 4) = o;
  } else {
    b -= NTOK;
    const int c0 = (b % 48) * 64;          // N = 3072
    const int r0 = (b / 48) * 64;          // M = 1024
    const int tx = threadIdx.x & 63;
    const int ty = threadIdx.x >> 6;
#pragma unroll
    for (int i = 0; i < 16; ++i) {
      int r = ty + i * 4;
      tile[r][tx] = wsrc[(size_t)(r0 + r) * 3072 + c0 + tx];
    }
    __syncthreads();
#pragma unroll
    for (int i = 0; i < 16; ++i) {
      int r = ty + i * 4;
      wdst[(size_t)(c0 + r) * 1024 + r0 + tx] = (bf16_t)tile[tx][r];
    }
  }
}

// ---------------- transpose + cast fp32 MxN -> bf16 NxM ----------------
__global__ __launch_bounds__(256) void k_tc(const float* __restrict__ src,
                                            bf16_t* __restrict__ dst,
                                            int M, int N) {
  __shared__ float tile[64][65];
  const int c0 = blockIdx.x * 64;
  const int r0 = blockIdx.y * 64;
  const int tx = threadIdx.x & 63;
  const int ty = threadIdx.x >> 6;
#pragma unroll
  for (int i = 0; i < 16; ++i) {
    int r = ty + i * 4;
    tile[r][tx] = src[(size_t)(r0 + r) * N + c0 + tx];
  }
  __syncthreads();
#pragma unroll
  for (int i = 0; i < 16; ++i) {
    int r = ty + i * 4;
    dst[(size_t)(c0 + r) * M + r0 + tx] = (bf16_t)tile[tx][r];
  }
}

// ---------------- GEMM 128x128 (m97 structure): C[M,N] = A[M,K] * Bt[N,K]^T ----------------
template <int F32OUT>
__global__ __launch_bounds__(256) void k_gemm_bt(const bf16_t* __restrict__ A,
                                                 const bf16_t* __restrict__ Bt,
                                                 bf16_t* __restrict__ Cb,
                                                 float* __restrict__ Cf,
                                                 const float* __restrict__ bias,
                                                 int M, int N, int K) {
  __shared__ alignas(16) bf16_t As[128 * 32];
  __shared__ alignas(16) bf16_t Bs[128 * 32];
  const int tid = threadIdx.x, lane = tid & 63, w = tid >> 6;
  const int bm = blockIdx.x * 128, bn = blockIdx.y * 128;
  const int wr = (w >> 1) * 64, wc = (w & 1) * 64;
  f32x4 acc[4][4];
#pragma unroll
  for (int i = 0; i < 4; ++i)
#pragma unroll
    for (int j = 0; j < 4; ++j) acc[i][j] = f32x4{0.f, 0.f, 0.f, 0.f};

  const int srow  = lane >> 2;
  const int scol8 = (lane & 3) * 8;

  for (int kt = 0; kt < K; kt += 32) {
    __syncthreads();
#pragma unroll
    for (int it = 0; it < 2; ++it) {
      int seg = w * 2 + it;
      int ar = bm + seg * 16 + srow;
      int br = bn + seg * 16 + srow;
      gload_lds16(A  + (size_t)ar * K + kt + scol8, (char*)As + seg * 1024 + lane * 16);
      gload_lds16(Bt + (size_t)br * K + kt + scol8, (char*)Bs + seg * 1024 + lane * 16);
    }
    __syncthreads();
    bf16x8 af[4], bfr[4];
#pragma unroll
    for (int i = 0; i < 4; ++i) {
      int mrow = wr + i * 16 + (lane & 15);
      af[i] = *reinterpret_cast<const bf16x8*>((const char*)As + mrow * 64 + (lane >> 4) * 16);
    }
#pragma unroll
    for (int j = 0; j < 4; ++j) {
      int nrow = wc + j * 16 + (lane & 15);
      bfr[j] = *reinterpret_cast<const bf16x8*>((const char*)Bs + nrow * 64 + (lane >> 4) * 16);
    }
#pragma unroll
    for (int i = 0; i < 4; ++i)
#pragma unroll
      for (int j = 0; j < 4; ++j)
        acc[i][j] = __builtin_amdgcn_mfma_f32_16x16x32_bf16(af[i], bfr[j], acc[i][j], 0, 0, 0);
  }

#pragma unroll
  for (int i = 0; i < 4; ++i)
#pragma unroll
    for (int j = 0; j < 4; ++j)
#pragma unroll
      for (int r = 0; r < 4; ++r) {
        int mm = bm + wr + i * 16 + (lane >> 4) * 4 + r;
        int nn = bn + wc + j * 16 + (lane & 15);
        float val = acc[i][j][r];
        if (F32OUT)
          Cf[(size_t)mm * N + nn] = val + bias[nn];
        else
          Cb[(size_t)mm * N + nn] = (bf16_t)val;
      }
}

// ---------------- GEMM 64x128 ----------------
template <int F32OUT>
__global__ __launch_bounds__(256) void k_gemm64(const bf16_t* __restrict__ A,
                                                const bf16_t* __restrict__ Bt,
                                                bf16_t* __restrict__ Cb,
                                                float* __restrict__ Cf,
                                                const float* __restrict__ bias,
                                                int M, int N, int K) {
  __shared__ alignas(16) bf16_t As[64 * 32];
  __shared__ alignas(16) bf16_t Bs[128 * 32];
  const int tid = threadIdx.x, lane = tid & 63, w = tid >> 6;
  const int bm = blockIdx.x * 64, bn = blockIdx.y * 128;
  const int wr = (w >> 1) * 32, wc = (w & 1) * 64;
  f32x4 acc[2][4];
#pragma unroll
  for (int i = 0; i < 2; ++i)
#pragma unroll
    for (int j = 0; j < 4; ++j) acc[i][j] = f32x4{0.f, 0.f, 0.f, 0.f};

  const int srow  = lane >> 2;
  const int scol8 = (lane & 3) * 8;

  for (int kt = 0; kt < K; kt += 32) {
    __syncthreads();
#pragma unroll
    for (int it = 0; it < 3; ++it) {
      int s = w * 3 + it;
      if (s < 4)
        gload_lds16(A + (size_t)(bm + s * 16 + srow) * K + kt + scol8,
                    (char*)As + s * 1024 + lane * 16);
      else
        gload_lds16(Bt + (size_t)(bn + (s - 4) * 16 + srow) * K + kt + scol8,
                    (char*)Bs + (s - 4) * 1024 + lane * 16);
    }
    __syncthreads();
    bf16x8 af[2], bfr[4];
#pragma unroll
    for (int i = 0; i < 2; ++i) {
      int mrow = wr + i * 16 + (lane & 15);
      af[i] = *reinterpret_cast<const bf16x8*>((const char*)As + mrow * 64 + (lane >> 4) * 16);
    }
#pragma unroll
    for (int j = 0; j < 4; ++j) {
      int nrow = wc + j * 16 + (lane & 15);
      bfr[j] = *reinterpret_cast<const bf16x8*>((const char*)Bs + nrow * 64 + (lane >> 4) * 16);
    }
#pragma unroll
    for (int i = 0; i < 2; ++i)
#pragma unroll
      for (int j = 0; j < 4; ++j)
        acc[i][j] = __builtin_amdgcn_mfma_f32_16x16x32_bf16(af[i], bfr[j], acc[i][j], 0, 0, 0);
  }

#pragma unroll
  for (int i = 0; i < 2; ++i)
#pragma unroll
    for (int j = 0; j < 4; ++j)
#pragma unroll
      for (int r = 0; r < 4; ++r) {
        int mm = bm + wr + i * 16 + (lane >> 4) * 4 + r;
        int nn = bn + wc + j * 16 + (lane & 15);
        float val = acc[i][j][r];
        if (F32OUT)
          Cf[(size_t)mm * N + nn] = val + bias[nn];
        else
          Cb[(size_t)mm * N + nn] = (bf16_t)val;
      }
}

// ---------------- fused: RoPE (q scaled by 1/32) + V transpose ----------------
__global__ __launch_bounds__(256) void k_rope_vt(bf16_t* __restrict__ qkv,
                                                 const float* __restrict__ psin,
                                                 const float* __restrict__ pcos,
                                                 bf16_t* __restrict__ Vt) {
  __shared__ bf16_t tile[64][72];
  int b = blockIdx.x;
  if (b < NTOK - 1) {
    const int i = b + 1;
    const int t = threadIdx.x;
#pragma unroll
    for (int itr = 0; itr < 4; ++itr) {
      int pidx = itr * 256 + t;
      int half = pidx >> 9;              // 0=q, 1=k
      int pp   = pidx & 511;
      int hh = pp >> 5, tt2 = pp & 31;
      size_t off = (size_t)i * QKVN + half * 1024 + hh * 64 + tt2 * 2;
      float sn = psin[(size_t)(i - 1) * 32 + tt2];
      float cs = pcos[(size_t)(i - 1) * 32 + tt2];
      unsigned int u = *reinterpret_cast<const unsigned int*>(qkv + off);
      float x0 = bf2f(__builtin_bit_cast(bf16_t, (unsigned short)(u & 0xffffu)));
      float x1 = bf2f(__builtin_bit_cast(bf16_t, (unsigned short)(u >> 16)));
      const float mul = half ? 1.0f : 0.03125f;   // fold softmax scale into q (exact 2^-5)
      unsigned short b0 = __builtin_bit_cast(unsigned short, (bf16_t)((x0 * cs - x1 * sn) * mul));
      unsigned short b1 = __builtin_bit_cast(unsigned short, (bf16_t)((x1 * cs + x0 * sn) * mul));
      *reinterpret_cast<unsigned int*>(qkv + off) = (unsigned int)b0 | ((unsigned int)b1 << 16);
    }
  } else {
    b -= (NTOK - 1);
    const int n0 = (b & 31) * 64;
    const int h  = b >> 5;
    const int r  = threadIdx.x >> 2;
    const int cq = threadIdx.x & 3;
    const bf16_t* src = qkv + (size_t)(n0 + r) * QKVN + 2048 + h * DH + cq * 16;
    bf16x8 v0 = *reinterpret_cast<const bf16x8*>(src);
    bf16x8 v1 = *reinterpret_cast<const bf16x8*>(src + 8);
#pragma unroll
    for (int e = 0; e < 8; ++e) { tile[r][cq * 16 + e] = v0[e]; tile[r][cq * 16 + 8 + e] = v1[e]; }
    __syncthreads();
    const int d = r;
    bf16x8 o0, o1;
#pragma unroll
    for (int e = 0; e < 8; ++e) { o0[e] = tile[cq * 16 + e][d]; o1[e] = tile[cq * 16 + 8 + e][d]; }
    bf16_t* dst = Vt + ((size_t)h * DH + d) * NTOK + n0 + cq * 16;
    *reinterpret_cast<bf16x8*>(dst)     = o0;
    *reinterpret_cast<bf16x8*>(dst + 8) = o1;
  }
}

// ---------------- flash attention partials: 128 q-rows x <=512 keys, 8 waves ----------------
__global__ __launch_bounds__(512) void k_attn_part(const bf16_t* __restrict__ qkv,
                                                   const bf16_t* __restrict__ Vt,
                                                   const int* __restrict__ mask,
                                                   char* __restrict__ part) {
  __shared__ alignas(16) bf16_t Ks[2][64][64];   // 16 KB
  __shared__ alignas(16) bf16_t Vs[2][64][64];   // 16 KB
  __shared__ alignas(16) bf16_t Ps[8][1024];     // 16 KB
  __shared__ unsigned char padc[512];

  const int h = blockIdx.y;
  const int slot = (SLOTS_PER_HEAD - 1) - blockIdx.x;   // heavy slots first
  int g;
  if (slot < 4) g = 0; else if (slot < 12) g = 1; else if (slot < 24) g = 2; else g = 3;
  const int tt = slot - 2 * g * (g + 1);
  const int Q = (g << 2) + tt / (g + 1);
  const int c = tt - (tt / (g + 1)) * (g + 1);
  const int q0 = Q * 128;
  const int kbeg = c * 512;
  const int kvlen = (Q + 1) * 128;
  const int klen = min(512, kvlen - kbeg);
  const int ntiles = klen >> 6;                 // 2,4,6,8

  const int tid = threadIdx.x, lane = tid & 63, w = tid >> 6;

  for (int jr = tid; jr < klen; jr += 512) {
    int j = kbeg + jr;
    padc[jr] = (j == 0) ? 1 : (unsigned char)(mask[j - 1] != 0);
  }

  const int iw = q0 + w * 16;                   // wave's first q-row
  bf16x8 qf[2];
  {
    const bf16_t* qp = qkv + (size_t)(iw + (lane & 15)) * QKVN + h * DH + (lane >> 4) * 8;
    qf[0] = *reinterpret_cast<const bf16x8*>(qp);
    qf[1] = *reinterpret_cast<const bf16x8*>(qp + 32);
  }
  bf16x8 ones;
#pragma unroll
  for (int e = 0; e < 8; ++e) ones[e] = (bf16_t)1.0f;

  float m_run[4], m2[4];
  f32x4 acc[4], accl;
#pragma unroll
  for (int r = 0; r < 4; ++r) { m_run[r] = -1e30f; m2[r] = -1e30f; }
#pragma unroll
  for (int df = 0; df < 4; ++df) acc[df] = f32x4{0.f, 0.f, 0.f, 0.f};
  accl = f32x4{0.f, 0.f, 0.f, 0.f};

  const int r8 = lane >> 3;
  const int sw = (lane & 7) ^ r8;

  // staging: 16 segs (0..7 K-rows, 8..15 V-rows); wave w stages segs 2w, 2w+1
#define STAGE(KB, BUF)                                                                   \
  {                                                                                      \
    _Pragma("unroll") for (int i2 = 0; i2 < 2; ++i2) {                                   \
      int s = w * 2 + i2;                                                                \
      if (s < 8) {                                                                       \
        int row = s * 8 + r8;                                                            \
        gload_lds16(qkv + (size_t)((KB) + row) * QKVN + DIM + h * DH + sw * 8,           \
                    (char*)Ks + (BUF)*8192 + s * 1024 + lane * 16);                      \
      } else {                                                                           \
        int row = (s - 8) * 8 + r8;                                                      \
        gload_lds16(Vt + ((size_t)h * DH + row) * NTOK + (KB) + sw * 8,                  \
                    (char*)Vs + (BUF)*8192 + (s - 8) * 1024 + lane * 16);                \
      }                                                                                  \
    }                                                                                    \
  }

  STAGE(kbeg, 0)

  for (int it = 0; it < ntiles; ++it) {
    const int buf = it & 1;
    if (it + 1 < ntiles) {
      STAGE(kbeg + (it + 1) * 64, buf ^ 1)
      asm volatile("s_waitcnt vmcnt(2)" ::: "memory");
    } else {
      asm volatile("s_waitcnt vmcnt(0)" ::: "memory");
    }
    __builtin_amdgcn_s_barrier();

    const int k0 = kbeg + it * 64;
    if (k0 <= iw + 15) {   // live tile for this wave
      const char* KsT = (const char*)Ks + buf * 8192;
      const char* VsT = (const char*)Vs + buf * 8192;

      f32x4 sfr[4];
      __builtin_amdgcn_s_setprio(1);
#pragma unroll
      for (int jf = 0; jf < 4; ++jf) {
        f32x4 s = f32x4{0.f, 0.f, 0.f, 0.f};
        int jl = jf * 16 + (lane & 15);
#pragma unroll
        for (int ks = 0; ks < 2; ++ks) {
          int inrow = (ks * 64 + (lane >> 4) * 16) ^ ((jl & 7) << 4);
          bf16x8 kf = *reinterpret_cast<const bf16x8*>(KsT + jl * 128 + inrow);
          s = __builtin_amdgcn_mfma_f32_16x16x32_bf16(qf[ks], kf, s, 0, 0, 0);
        }
        sfr[jf] = s;
      }
      __builtin_amdgcn_s_setprio(0);

      // local max (raw scores; masked entries may inflate m harmlessly)
      float pmax[4] = {-3e38f, -3e38f, -3e38f, -3e38f};
#pragma unroll
      for (int jf = 0; jf < 4; ++jf)
#pragma unroll
        for (int r = 0; r < 4; ++r) pmax[r] = fmaxf(pmax[r], sfr[jf][r]);

      int dok = (pmax[0] <= m_run[0] + 8.f) && (pmax[1] <= m_run[1] + 8.f) &&
                (pmax[2] <= m_run[2] + 8.f) && (pmax[3] <= m_run[3] + 8.f);
      if (!__all(dok)) {
#pragma unroll
        for (int o = 1; o < 16; o <<= 1)
#pragma unroll
          for (int r = 0; r < 4; ++r) pmax[r] = fmaxf(pmax[r], __shfl_xor(pmax[r], o, 64));
#pragma unroll
        for (int r = 0; r < 4; ++r) {
          float mnew = fmaxf(m_run[r], pmax[r]);
          float corr = __builtin_amdgcn_exp2f((m_run[r] - mnew) * L2E);
          m_run[r] = mnew;
          m2[r] = mnew * L2E;
          accl[r] *= corr;
#pragma unroll
          for (int df = 0; df < 4; ++df) acc[df][r] *= corr;
        }
      }

      const bool needC = (k0 + 63 > iw);
#pragma unroll
      for (int jf = 0; jf < 4; ++jf) {
        int jl = jf * 16 + (lane & 15);
        int j = k0 + jl;
        bool padj = padc[j - kbeg] != 0;
#pragma unroll
        for (int r = 0; r < 4; ++r) {
          float pe = __builtin_amdgcn_exp2f(__builtin_fmaf(sfr[jf][r], L2E, -m2[r]));
          bool ok = padj;
          if (needC) ok = ok && (j <= iw + (lane >> 4) * 4 + r);
          pe = ok ? pe : 0.f;
          int m = (lane >> 4) * 4 + r;
          *reinterpret_cast<bf16_t*>((char*)&Ps[w][0] + m * 128 + ((jl * 2) ^ ((m & 7) << 4))) =
              (bf16_t)pe;
        }
      }

      // O += P V ; l += P 1 (ones-column)
      __builtin_amdgcn_s_setprio(1);
#pragma unroll
      for (int ks = 0; ks < 2; ++ks) {
        int mm = lane & 15;
        int inrow = (ks * 64 + (lane >> 4) * 16) ^ ((mm & 7) << 4);
        bf16x8 pa = *reinterpret_cast<const bf16x8*>((const char*)&Ps[w][0] + mm * 128 + inrow);
        accl = __builtin_amdgcn_mfma_f32_16x16x32_bf16(pa, ones, accl, 0, 0, 0);
#pragma unroll
        for (int df = 0; df < 4; ++df) {
          int d = df * 16 + (lane & 15);
          int vin = (ks * 64 + (lane >> 4) * 16) ^ ((d & 7) << 4);
          bf16x8 vf = *reinterpret_cast<const bf16x8*>(VsT + d * 128 + vin);
          acc[df] = __builtin_amdgcn_mfma_f32_16x16x32_bf16(pa, vf, acc[df], 0, 0, 0);
        }
      }
      __builtin_amdgcn_s_setprio(0);
    }
    __builtin_amdgcn_s_barrier();
  }
#undef STAGE

  char* pb = part + (size_t)(h * SLOTS_PER_HEAD + slot) * PART_STRIDE;
  bf16_t* po = (bf16_t*)pb;
  float* pm = (float*)(pb + 16384);
  float* pl = (float*)(pb + 16896);
#pragma unroll
  for (int df = 0; df < 4; ++df)
#pragma unroll
    for (int r = 0; r < 4; ++r) {
      int row = w * 16 + (lane >> 4) * 4 + r;
      po[row * 64 + df * 16 + (lane & 15)] = (bf16_t)acc[df][r];
    }
  if ((lane & 15) == 0) {
#pragma unroll
    for (int r = 0; r < 4; ++r) {
      int row = w * 16 + (lane >> 4) * 4 + r;
      pm[row] = m2[r];       // log2 units
      pl[row] = accl[r];
    }
  }
}

// ---------------- merge partials -> Ob ----------------
// grid (16, 16): block = (Q, head). thread owns (row = t>>1, 32 dims).
__global__ __launch_bounds__(256) void k_merge(const char* __restrict__ part,
                                               bf16_t* __restrict__ Ob) {
  const int Q = blockIdx.x, h = blockIdx.y;
  const int g = Q >> 2, nch = g + 1;
  const int cum = 2 * g * (g + 1) + (Q & 3) * nch;
  const int t = threadIdx.x;
  const int row = t >> 1, half = t & 1;

  float acc[32];
#pragma unroll
  for (int e = 0; e < 32; ++e) acc[e] = 0.f;
  float M = -3e38f, L = 0.f;

  for (int c = 0; c < nch; ++c) {
    const char* pb = part + (size_t)(h * SLOTS_PER_HEAD + cum + c) * PART_STRIDE;
    float mc = ((const float*)(pb + 16384))[row];
    float lc = ((const float*)(pb + 16896))[row];
    float Mn = fmaxf(M, mc);
    float sOld = __builtin_amdgcn_exp2f(M - Mn), sNew = __builtin_amdgcn_exp2f(mc - Mn);
    M = Mn;
    L = L * sOld + lc * sNew;
    const bf16_t* od = (const bf16_t*)pb + row * 64 + half * 32;
#pragma unroll
    for (int e4 = 0; e4 < 4; ++e4) {
      bf16x8 o8 = *reinterpret_cast<const bf16x8*>(od + e4 * 8);
#pragma unroll
      for (int e = 0; e < 8; ++e)
        acc[e4 * 8 + e] = acc[e4 * 8 + e] * sOld + (float)o8[e] * sNew;
    }
  }
  const float inv = 1.0f / L;
  bf16_t* dst = Ob + (size_t)(Q * 128 + row) * DIM + h * DH + half * 32;
#pragma unroll
  for (int e4 = 0; e4 < 4; ++e4) {
    bf16x8 r8o;
#pragma unroll
    for (int e = 0; e < 8; ++e) r8o[e] = (bf16_t)(acc[e4 * 8 + e] * inv);
    *reinterpret_cast<bf16x8*>(dst + e4 * 8) = r8o;
  }
}

// ---------------- row 0 (non-causal: attends all keys) ----------------
__global__ __launch_bounds__(256) void k_row0(const bf16_t* __restrict__ qkv,
                                              const bf16_t* __restrict__ Vt,
                                              const int* __restrict__ mask,
                                              bf16_t* __restrict__ Ob) {
  __shared__ float qv[64];
  __shared__ float sbuf[2048];
  __shared__ float red[4];
  __shared__ float red2[4][64];
  const int h = blockIdx.x, t = threadIdx.x, lane = t & 63, w = t >> 6;
  if (t < 64) qv[t] = (float)qkv[h * DH + t];   // row 0 q, un-roped & un-scaled
  __syncthreads();

  float sm[8];
  float lmax = -1e30f;
#pragma unroll
  for (int p = 0; p < 8; ++p) {
    int j = p * 256 + t;
    const bf16_t* kr = qkv + (size_t)j * QKVN + DIM + h * DH;
    float s = 0.f;
#pragma unroll
    for (int u = 0; u < 8; ++u) {
      bf16x8 kv8 = *reinterpret_cast<const bf16x8*>(kr + u * 8);
#pragma unroll
      for (int e = 0; e < 8; ++e) s += qv[u * 8 + e] * (float)kv8[e];
    }
    bool padj = (j == 0) || (mask[j - 1] != 0);
    s = padj ? s * 0.03125f : -1e30f;
    sm[p] = s;
    lmax = fmaxf(lmax, s);
  }
#pragma unroll
  for (int o = 1; o < 64; o <<= 1) lmax = fmaxf(lmax, __shfl_xor(lmax, o, 64));
  if (lane == 0) red[w] = lmax;
  __syncthreads();
  const float M = fmaxf(fmaxf(red[0], red[1]), fmaxf(red[2], red[3]));
  float ls = 0.f;
#pragma unroll
  for (int p = 0; p < 8; ++p) {
    float pe = __expf(sm[p] - M);
    sbuf[p * 256 + t] = pe;
    ls += pe;
  }
#pragma unroll
  for (int o = 1; o < 64; o <<= 1) ls += __shfl_xor(ls, o, 64);
  __syncthreads();
  if (lane == 0) red[w] = ls;
  __syncthreads();
  const float L = red[0] + red[1] + red[2] + red[3];

  const int d = t & 63, qr = t >> 6;
  const bf16_t* vr = Vt + ((size_t)h * DH + d) * NTOK + qr * 512;
  float a = 0.f;
#pragma unroll 8
  for (int u = 0; u < 64; ++u) {
    bf16x8 v8 = *reinterpret_cast<const bf16x8*>(vr + u * 8);
#pragma unroll
    for (int e = 0; e < 8; ++e) a += sbuf[qr * 512 + u * 8 + e] * (float)v8[e];
  }
  red2[qr][d] = a;
  __syncthreads();
  if (t < 64) {
    float o = (red2[0][t] + red2[1][t] + red2[2][t] + red2[3][t]) / L;
    Ob[h * DH + t] = (bf16_t)o;
  }
}

// ---------------- host ----------------
extern "C" void kernel_launch(void* const* d_in, const int* in_sizes, int n_in,
                              void* d_out, int out_size, void* d_ws, size_t ws_size,
                              hipStream_t stream) {
  const float* x       = (const float*)d_in[0];
  const float* pos_sin = (const float*)d_in[1];
  const float* pos_cos = (const float*)d_in[2];
  const int*   mask    = (const int*)d_in[3];
  const float* ln_s    = (const float*)d_in[4];
  const float* ln_b    = (const float*)d_in[5];
  const float* w_qkv   = (const float*)d_in[6];
  const float* w_out   = (const float*)d_in[7];
  const float* b_out   = (const float*)d_in[8];
  float* out = (float*)d_out;

  if (ws_size < 33554432u) return;

  char* ws = (char*)d_ws;
  bf16_t* qkv  = (bf16_t*)(ws + 0);           // 12 MiB
  bf16_t* Vt   = (bf16_t*)(ws + 12582912);    //  4 MiB
  bf16_t* Ob   = (bf16_t*)(ws + 16777216);    //  4 MiB
  char*   part = ws + 20971520;               // 10.63 MiB (16*40*17408)
  bf16_t* xn   = (bf16_t*)(ws + 20971520);    //  4 MiB, dead before part written
  bf16_t* Wqt  = (bf16_t*)(ws + 25165824);    //  6 MiB, dead before part written
  bf16_t* Wot  = (bf16_t*)(ws + 20971520);    //  2 MiB, written after merge (part dead)

  k_ln_tc<<<NTOK + 768, 256, 0, stream>>>(x, ln_s, ln_b, xn, w_qkv, Wqt);
  k_gemm_bt<0><<<dim3(16, 24), 256, 0, stream>>>(xn, Wqt, qkv, nullptr, nullptr,
                                                 NTOK, QKVN, DIM);
  k_rope_vt<<<(NTOK - 1) + 512, 256, 0, stream>>>(qkv, pos_sin, pos_cos, Vt);
  k_attn_part<<<dim3(SLOTS_PER_HEAD, NH), 512, 0, stream>>>(qkv, Vt, mask, part);
  k_merge<<<dim3(16, 16), 256, 0, stream>>>(part, Ob);
  k_tc<<<dim3(16, 16), 256, 0, stream>>>(w_out, Wot, 1024, 1024);
  k_row0<<<NH, 256, 0, stream>>>(qkv, Vt, mask, Ob);
  k_gemm64<1><<<dim3(32, 8), 256, 0, stream>>>(Ob, Wot, nullptr, out, b_out,
                                               NTOK, DIM, DIM);
}

// Round 7
// 105.675 us; speedup vs baseline: 1.3062x; 1.3062x over previous
//
#include <hip/hip_runtime.h>
#include <hip/hip_bf16.h>
#include <stdint.h>

typedef __bf16 bf16_t;
typedef __bf16 bf16x8 __attribute__((ext_vector_type(8)));
typedef __bf16 bf16x4 __attribute__((ext_vector_type(4)));
typedef float  f32x4  __attribute__((ext_vector_type(4)));

#define DEV __device__ __forceinline__

static constexpr int NTOK = 2048;
static constexpr int DIM  = 1024;
static constexpr int NH   = 16;
static constexpr int DH   = 64;
static constexpr int QKVN = 3072;
static constexpr int SLOTS_PER_HEAD = 40;   // sum over Q=0..15 of ceil((Q+1)/4)
static constexpr int PART_SLOTS = 36;       // slots 4..39 go through part/merge
static constexpr int PART_STRIDE = 17408;   // 128x64 bf16 (16384) + m2[128] f32 + l[128] f32
static constexpr float L2E = 1.44269504f;

DEV void gload_lds16(const void* g, void* l) {
  __builtin_amdgcn_global_load_lds(
      (__attribute__((address_space(1))) void*)(g),
      (__attribute__((address_space(3))) void*)(l), 16, 0, 0);
}

DEV float bf2f(bf16_t b) { return (float)b; }

// ---- fused: LayerNorm (0..2047) + w_qkv T (2048..2815) + w_out T (2816..3071) ----
__global__ __launch_bounds__(256) void k_ln_tc(const float* __restrict__ x,
                                               const float* __restrict__ gamma,
                                               const float* __restrict__ beta,
                                               bf16_t* __restrict__ xn,
                                               const float* __restrict__ wsrc,
                                               bf16_t* __restrict__ wdst,
                                               const float* __restrict__ wosrc,
                                               bf16_t* __restrict__ wodst) {
  __shared__ float tile[64][65];
  __shared__ float red[8];
  int b = blockIdx.x;
  if (b < NTOK) {
    const int row = b;
    const int t = threadIdx.x;
    const float4* x4 = reinterpret_cast<const float4*>(x);
    float4 v = x4[(size_t)row * 256 + t];
    float s  = v.x + v.y + v.z + v.w;
    float s2 = v.x * v.x + v.y * v.y + v.z * v.z + v.w * v.w;
#pragma unroll
    for (int o = 1; o < 64; o <<= 1) {
      s  += __shfl_xor(s, o, 64);
      s2 += __shfl_xor(s2, o, 64);
    }
    const int w = t >> 6, lane = t & 63;
    if (lane == 0) { red[w] = s; red[4 + w] = s2; }
    __syncthreads();
    s  = red[0] + red[1] + red[2] + red[3];
    s2 = red[4] + red[5] + red[6] + red[7];
    const float mu  = s * (1.0f / 1024.0f);
    const float var = s2 * (1.0f / 1024.0f) - mu * mu;
    const float inv = rsqrtf(var + 1e-6f);
    const float4 g = reinterpret_cast<const float4*>(gamma)[t];
    const float4 bb = reinterpret_cast<const float4*>(beta)[t];
    bf16x4 o;
    o[0] = (bf16_t)((v.x - mu) * inv * g.x + bb.x);
    o[1] = (bf16_t)((v.y - mu) * inv * g.y + bb.y);
    o[2] = (bf16_t)((v.z - mu) * inv * g.z + bb.z);
    o[3] = (bf16_t)((v.w - mu) * inv * g.w + bb.w);
    *reinterpret_cast<bf16x4*>(xn + (size_t)row * DIM + t * 4) = o;
  } else if (b < NTOK + 768) {
    b -= NTOK;
    const int c0 = (b % 48) * 64;          // N = 3072
    const int r0 = (b / 48) * 64;          // M = 1024
    const int tx = threadIdx.x & 63;
    const int ty = threadIdx.x >> 6;
#pragma unroll
    for (int i = 0; i < 16; ++i) {
      int r = ty + i * 4;
      tile[r][tx] = wsrc[(size_t)(r0 + r) * 3072 + c0 + tx];
    }
    __syncthreads();
#pragma unroll
    for (int i = 0; i < 16; ++i) {
      int r = ty + i * 4;
      wdst[(size_t)(c0 + r) * 1024 + r0 + tx] = (bf16_t)tile[tx][r];
    }
  } else {
    b -= (NTOK + 768);
    const int c0 = (b & 15) * 64;          // N = 1024
    const int r0 = (b >> 4) * 64;          // M = 1024
    const int tx = threadIdx.x & 63;
    const int ty = threadIdx.x >> 6;
#pragma unroll
    for (int i = 0; i < 16; ++i) {
      int r = ty + i * 4;
      tile[r][tx] = wosrc[(size_t)(r0 + r) * 1024 + c0 + tx];
    }
    __syncthreads();
#pragma unroll
    for (int i = 0; i < 16; ++i) {
      int r = ty + i * 4;
      wodst[(size_t)(c0 + r) * 1024 + r0 + tx] = (bf16_t)tile[tx][r];
    }
  }
}

// ---- GEMM 128x128, 2-phase double-buffered: C[M,N] = A[M,K] * Bt[N,K]^T ----
template <int F32OUT>
__global__ __launch_bounds__(256) void k_gemm_bt(const bf16_t* __restrict__ A,
                                                 const bf16_t* __restrict__ Bt,
                                                 bf16_t* __restrict__ Cb,
                                                 float* __restrict__ Cf,
                                                 const float* __restrict__ bias,
                                                 int M, int N, int K) {
  __shared__ alignas(16) bf16_t As[2][128 * 32];   // 2 x 8 KB
  __shared__ alignas(16) bf16_t Bs[2][128 * 32];   // 2 x 8 KB
  const int tid = threadIdx.x, lane = tid & 63, w = tid >> 6;
  const int bm = blockIdx.x * 128, bn = blockIdx.y * 128;
  const int wr = (w >> 1) * 64, wc = (w & 1) * 64;
  f32x4 acc[4][4];
#pragma unroll
  for (int i = 0; i < 4; ++i)
#pragma unroll
    for (int j = 0; j < 4; ++j) acc[i][j] = f32x4{0.f, 0.f, 0.f, 0.f};

  const int srow  = lane >> 2;
  const int scol8 = (lane & 3) * 8;

#define GSTAGE(KT, BUF)                                                               \
  {                                                                                   \
    _Pragma("unroll") for (int it = 0; it < 2; ++it) {                                \
      int seg = w * 2 + it;                                                           \
      gload_lds16(A + (size_t)(bm + seg * 16 + srow) * K + (KT) + scol8,              \
                  (char*)As + (BUF) * 8192 + seg * 1024 + lane * 16);                 \
      gload_lds16(Bt + (size_t)(bn + seg * 16 + srow) * K + (KT) + scol8,             \
                  (char*)Bs + (BUF) * 8192 + seg * 1024 + lane * 16);                 \
    }                                                                                 \
  }

  GSTAGE(0, 0)
  __syncthreads();
  int buf = 0;
  for (int kt = 0; kt < K; kt += 32, buf ^= 1) {
    if (kt + 32 < K) GSTAGE(kt + 32, buf ^ 1)
    bf16x8 af[4], bfr[4];
#pragma unroll
    for (int i = 0; i < 4; ++i) {
      int mrow = wr + i * 16 + (lane & 15);
      af[i] = *reinterpret_cast<const bf16x8*>((const char*)As + buf * 8192 + mrow * 64 +
                                               (lane >> 4) * 16);
    }
#pragma unroll
    for (int j = 0; j < 4; ++j) {
      int nrow = wc + j * 16 + (lane & 15);
      bfr[j] = *reinterpret_cast<const bf16x8*>((const char*)Bs + buf * 8192 + nrow * 64 +
                                                (lane >> 4) * 16);
    }
#pragma unroll
    for (int i = 0; i < 4; ++i)
#pragma unroll
      for (int j = 0; j < 4; ++j)
        acc[i][j] = __builtin_amdgcn_mfma_f32_16x16x32_bf16(af[i], bfr[j], acc[i][j], 0, 0, 0);
    __syncthreads();
  }
#undef GSTAGE

#pragma unroll
  for (int i = 0; i < 4; ++i)
#pragma unroll
    for (int j = 0; j < 4; ++j)
#pragma unroll
      for (int r = 0; r < 4; ++r) {
        int mm = bm + wr + i * 16 + (lane >> 4) * 4 + r;
        int nn = bn + wc + j * 16 + (lane & 15);
        float val = acc[i][j][r];
        if (F32OUT)
          Cf[(size_t)mm * N + nn] = val + bias[nn];
        else
          Cb[(size_t)mm * N + nn] = (bf16_t)val;
      }
}

// ---- GEMM 64x128, 2-phase double-buffered ----
template <int F32OUT>
__global__ __launch_bounds__(256) void k_gemm64(const bf16_t* __restrict__ A,
                                                const bf16_t* __restrict__ Bt,
                                                bf16_t* __restrict__ Cb,
                                                float* __restrict__ Cf,
                                                const float* __restrict__ bias,
                                                int M, int N, int K) {
  __shared__ alignas(16) bf16_t As[2][64 * 32];    // 2 x 4 KB
  __shared__ alignas(16) bf16_t Bs[2][128 * 32];   // 2 x 8 KB
  const int tid = threadIdx.x, lane = tid & 63, w = tid >> 6;
  const int bm = blockIdx.x * 64, bn = blockIdx.y * 128;
  const int wr = (w >> 1) * 32, wc = (w & 1) * 64;
  f32x4 acc[2][4];
#pragma unroll
  for (int i = 0; i < 2; ++i)
#pragma unroll
    for (int j = 0; j < 4; ++j) acc[i][j] = f32x4{0.f, 0.f, 0.f, 0.f};

  const int srow  = lane >> 2;
  const int scol8 = (lane & 3) * 8;

#define GSTAGE64(KT, BUF)                                                             \
  {                                                                                   \
    _Pragma("unroll") for (int it = 0; it < 3; ++it) {                                \
      int s = w * 3 + it;                                                             \
      if (s < 4)                                                                      \
        gload_lds16(A + (size_t)(bm + s * 16 + srow) * K + (KT) + scol8,              \
                    (char*)As + (BUF) * 4096 + s * 1024 + lane * 16);                 \
      else                                                                            \
        gload_lds16(Bt + (size_t)(bn + (s - 4) * 16 + srow) * K + (KT) + scol8,       \
                    (char*)Bs + (BUF) * 8192 + (s - 4) * 1024 + lane * 16);           \
    }                                                                                 \
  }

  GSTAGE64(0, 0)
  __syncthreads();
  int buf = 0;
  for (int kt = 0; kt < K; kt += 32, buf ^= 1) {
    if (kt + 32 < K) GSTAGE64(kt + 32, buf ^ 1)
    bf16x8 af[2], bfr[4];
#pragma unroll
    for (int i = 0; i < 2; ++i) {
      int mrow = wr + i * 16 + (lane & 15);
      af[i] = *reinterpret_cast<const bf16x8*>((const char*)As + buf * 4096 + mrow * 64 +
                                               (lane >> 4) * 16);
    }
#pragma unroll
    for (int j = 0; j < 4; ++j) {
      int nrow = wc + j * 16 + (lane & 15);
      bfr[j] = *reinterpret_cast<const bf16x8*>((const char*)Bs + buf * 8192 + nrow * 64 +
                                                (lane >> 4) * 16);
    }
#pragma unroll
    for (int i = 0; i < 2; ++i)
#pragma unroll
      for (int j = 0; j < 4; ++j)
        acc[i][j] = __builtin_amdgcn_mfma_f32_16x16x32_bf16(af[i], bfr[j], acc[i][j], 0, 0, 0);
    __syncthreads();
  }
#undef GSTAGE64

#pragma unroll
  for (int i = 0; i < 2; ++i)
#pragma unroll
    for (int j = 0; j < 4; ++j)
#pragma unroll
      for (int r = 0; r < 4; ++r) {
        int mm = bm + wr + i * 16 + (lane >> 4) * 4 + r;
        int nn = bn + wc + j * 16 + (lane & 15);
        float val = acc[i][j][r];
        if (F32OUT)
          Cf[(size_t)mm * N + nn] = val + bias[nn];
        else
          Cb[(size_t)mm * N + nn] = (bf16_t)val;
      }
}

// ---- fused: RoPE (q scaled by 1/32) + V transpose ----
__global__ __launch_bounds__(256) void k_rope_vt(bf16_t* __restrict__ qkv,
                                                 const float* __restrict__ psin,
                                                 const float* __restrict__ pcos,
                                                 bf16_t* __restrict__ Vt) {
  __shared__ bf16_t tile[64][72];
  int b = blockIdx.x;
  if (b < NTOK - 1) {
    const int i = b + 1;
    const int t = threadIdx.x;
#pragma unroll
    for (int itr = 0; itr < 4; ++itr) {
      int pidx = itr * 256 + t;
      int half = pidx >> 9;              // 0=q, 1=k
      int pp   = pidx & 511;
      int hh = pp >> 5, tt2 = pp & 31;
      size_t off = (size_t)i * QKVN + half * 1024 + hh * 64 + tt2 * 2;
      float sn = psin[(size_t)(i - 1) * 32 + tt2];
      float cs = pcos[(size_t)(i - 1) * 32 + tt2];
      unsigned int u = *reinterpret_cast<const unsigned int*>(qkv + off);
      float x0 = bf2f(__builtin_bit_cast(bf16_t, (unsigned short)(u & 0xffffu)));
      float x1 = bf2f(__builtin_bit_cast(bf16_t, (unsigned short)(u >> 16)));
      const float mul = half ? 1.0f : 0.03125f;   // fold softmax scale into q (exact 2^-5)
      unsigned short b0 = __builtin_bit_cast(unsigned short, (bf16_t)((x0 * cs - x1 * sn) * mul));
      unsigned short b1 = __builtin_bit_cast(unsigned short, (bf16_t)((x1 * cs + x0 * sn) * mul));
      *reinterpret_cast<unsigned int*>(qkv + off) = (unsigned int)b0 | ((unsigned int)b1 << 16);
    }
  } else {
    b -= (NTOK - 1);
    const int n0 = (b & 31) * 64;
    const int h  = b >> 5;
    const int r  = threadIdx.x >> 2;
    const int cq = threadIdx.x & 3;
    const bf16_t* src = qkv + (size_t)(n0 + r) * QKVN + 2048 + h * DH + cq * 16;
    bf16x8 v0 = *reinterpret_cast<const bf16x8*>(src);
    bf16x8 v1 = *reinterpret_cast<const bf16x8*>(src + 8);
#pragma unroll
    for (int e = 0; e < 8; ++e) { tile[r][cq * 16 + e] = v0[e]; tile[r][cq * 16 + 8 + e] = v1[e]; }
    __syncthreads();
    const int d = r;
    bf16x8 o0, o1;
#pragma unroll
    for (int e = 0; e < 8; ++e) { o0[e] = tile[cq * 16 + e][d]; o1[e] = tile[cq * 16 + 8 + e][d]; }
    bf16_t* dst = Vt + ((size_t)h * DH + d) * NTOK + n0 + cq * 16;
    *reinterpret_cast<bf16x8*>(dst)     = o0;
    *reinterpret_cast<bf16x8*>(dst + 8) = o1;
  }
}

// ---- flash attention partials + fused row-0 handler ----
// grid (41, 16), 512 thr. bx<40: slot (heavy-first); bx==40: non-causal row 0.
__global__ __launch_bounds__(512) void k_attn_part(const bf16_t* __restrict__ qkv,
                                                   const bf16_t* __restrict__ Vt,
                                                   const int* __restrict__ mask,
                                                   char* __restrict__ part,
                                                   bf16_t* __restrict__ Ob) {
  __shared__ alignas(16) bf16_t Ks[2][64][64];   // 16 KB
  __shared__ alignas(16) bf16_t Vs[2][64][64];   // 16 KB
  __shared__ alignas(16) bf16_t Ps[8][1024];     // 16 KB
  __shared__ unsigned char padc[512];

  const int h = blockIdx.y;

  if (blockIdx.x == SLOTS_PER_HEAD) {
    // ---------------- row 0: attends ALL 2048 keys, q un-roped/un-scaled ----------------
    float* qv   = (float*)Ps;        // 64 f32
    float* sbuf = (float*)Ks;        // 2048 f32 (8 KB < 16 KB)
    float* red  = (float*)Vs;        // 8 f32
    float* red2 = (float*)Vs + 64;   // 512 f32
    const int t = threadIdx.x, lane = t & 63, w8 = t >> 6;
    if (t < 64) qv[t] = (float)qkv[h * DH + t];
    __syncthreads();
    float sm[4];
    float lmax = -1e30f;
#pragma unroll
    for (int p = 0; p < 4; ++p) {
      int j = p * 512 + t;
      const bf16_t* kr = qkv + (size_t)j * QKVN + DIM + h * DH;
      float s = 0.f;
#pragma unroll
      for (int u = 0; u < 8; ++u) {
        bf16x8 kv8 = *reinterpret_cast<const bf16x8*>(kr + u * 8);
#pragma unroll
        for (int e = 0; e < 8; ++e) s += qv[u * 8 + e] * (float)kv8[e];
      }
      bool padj = (j == 0) || (mask[j - 1] != 0);
      s = padj ? s * 0.03125f : -1e30f;
      sm[p] = s;
      lmax = fmaxf(lmax, s);
    }
#pragma unroll
    for (int o = 1; o < 64; o <<= 1) lmax = fmaxf(lmax, __shfl_xor(lmax, o, 64));
    if (lane == 0) red[w8] = lmax;
    __syncthreads();
    float M = red[0];
#pragma unroll
    for (int i = 1; i < 8; ++i) M = fmaxf(M, red[i]);
    __syncthreads();   // everyone has read red before it's overwritten
    float ls = 0.f;
#pragma unroll
    for (int p = 0; p < 4; ++p) {
      float pe = __expf(sm[p] - M);
      sbuf[p * 512 + t] = pe;
      ls += pe;
    }
#pragma unroll
    for (int o = 1; o < 64; o <<= 1) ls += __shfl_xor(ls, o, 64);
    if (lane == 0) red[w8] = ls;
    __syncthreads();
    float L = red[0];
#pragma unroll
    for (int i = 1; i < 8; ++i) L += red[i];

    const int d = t & 63, qr = t >> 6;          // qr 0..7, 256 keys each
    const bf16_t* vr = Vt + ((size_t)h * DH + d) * NTOK + qr * 256;
    float a = 0.f;
#pragma unroll 8
    for (int u = 0; u < 32; ++u) {
      bf16x8 v8 = *reinterpret_cast<const bf16x8*>(vr + u * 8);
#pragma unroll
      for (int e = 0; e < 8; ++e) a += sbuf[qr * 256 + u * 8 + e] * (float)v8[e];
    }
    red2[qr * 64 + d] = a;
    __syncthreads();
    if (t < 64) {
      float o = 0.f;
#pragma unroll
      for (int i = 0; i < 8; ++i) o += red2[i * 64 + t];
      Ob[h * DH + t] = (bf16_t)(o / L);
    }
    return;
  }

  const int slot = (SLOTS_PER_HEAD - 1) - blockIdx.x;   // heavy slots first
  int g;
  if (slot < 4) g = 0; else if (slot < 12) g = 1; else if (slot < 24) g = 2; else g = 3;
  const int tt = slot - 2 * g * (g + 1);
  const int Q = (g << 2) + tt / (g + 1);
  const int c = tt - (tt / (g + 1)) * (g + 1);
  const int q0 = Q * 128;
  const int kbeg = c * 512;
  const int kvlen = (Q + 1) * 128;
  const int klen = min(512, kvlen - kbeg);
  const int ntiles = klen >> 6;                 // 2,4,6,8
  const int nch = g + 1;                        // chunks for this Q

  const int tid = threadIdx.x, lane = tid & 63, w = tid >> 6;

  for (int jr = tid; jr < klen; jr += 512) {
    int j = kbeg + jr;
    padc[jr] = (j == 0) ? 1 : (unsigned char)(mask[j - 1] != 0);
  }

  const int iw = q0 + w * 16;                   // wave's first q-row
  bf16x8 qf[2];
  {
    const bf16_t* qp = qkv + (size_t)(iw + (lane & 15)) * QKVN + h * DH + (lane >> 4) * 8;
    qf[0] = *reinterpret_cast<const bf16x8*>(qp);
    qf[1] = *reinterpret_cast<const bf16x8*>(qp + 32);
  }
  bf16x8 ones;
#pragma unroll
  for (int e = 0; e < 8; ++e) ones[e] = (bf16_t)1.0f;

  float m_run[4], m2[4];
  f32x4 acc[4], accl;
#pragma unroll
  for (int r = 0; r < 4; ++r) { m_run[r] = -1e30f; m2[r] = -1e30f; }
#pragma unroll
  for (int df = 0; df < 4; ++df) acc[df] = f32x4{0.f, 0.f, 0.f, 0.f};
  accl = f32x4{0.f, 0.f, 0.f, 0.f};

  const int r8 = lane >> 3;
  const int sw = (lane & 7) ^ r8;

#define STAGE(KB, BUF)                                                                   \
  {                                                                                      \
    _Pragma("unroll") for (int i2 = 0; i2 < 2; ++i2) {                                   \
      int s = w * 2 + i2;                                                                \
      if (s < 8) {                                                                       \
        int row = s * 8 + r8;                                                            \
        gload_lds16(qkv + (size_t)((KB) + row) * QKVN + DIM + h * DH + sw * 8,           \
                    (char*)Ks + (BUF)*8192 + s * 1024 + lane * 16);                      \
      } else {                                                                           \
        int row = (s - 8) * 8 + r8;                                                      \
        gload_lds16(Vt + ((size_t)h * DH + row) * NTOK + (KB) + sw * 8,                  \
                    (char*)Vs + (BUF)*8192 + (s - 8) * 1024 + lane * 16);                \
      }                                                                                  \
    }                                                                                    \
  }

  STAGE(kbeg, 0)

  for (int it = 0; it < ntiles; ++it) {
    const int buf = it & 1;
    if (it + 1 < ntiles) {
      STAGE(kbeg + (it + 1) * 64, buf ^ 1)
      asm volatile("s_waitcnt vmcnt(2)" ::: "memory");
    } else {
      asm volatile("s_waitcnt vmcnt(0)" ::: "memory");
    }
    __builtin_amdgcn_s_barrier();

    const int k0 = kbeg + it * 64;
    if (k0 <= iw + 15) {   // live tile for this wave
      const char* KsT = (const char*)Ks + buf * 8192;
      const char* VsT = (const char*)Vs + buf * 8192;

      f32x4 sfr[4];
      __builtin_amdgcn_s_setprio(1);
#pragma unroll
      for (int jf = 0; jf < 4; ++jf) {
        f32x4 s = f32x4{0.f, 0.f, 0.f, 0.f};
        int jl = jf * 16 + (lane & 15);
#pragma unroll
        for (int ks = 0; ks < 2; ++ks) {
          int inrow = (ks * 64 + (lane >> 4) * 16) ^ ((jl & 7) << 4);
          bf16x8 kf = *reinterpret_cast<const bf16x8*>(KsT + jl * 128 + inrow);
          s = __builtin_amdgcn_mfma_f32_16x16x32_bf16(qf[ks], kf, s, 0, 0, 0);
        }
        sfr[jf] = s;
      }
      __builtin_amdgcn_s_setprio(0);

      float pmax[4] = {-3e38f, -3e38f, -3e38f, -3e38f};
#pragma unroll
      for (int jf = 0; jf < 4; ++jf)
#pragma unroll
        for (int r = 0; r < 4; ++r) pmax[r] = fmaxf(pmax[r], sfr[jf][r]);

      int dok = (pmax[0] <= m_run[0] + 8.f) && (pmax[1] <= m_run[1] + 8.f) &&
                (pmax[2] <= m_run[2] + 8.f) && (pmax[3] <= m_run[3] + 8.f);
      if (!__all(dok)) {
#pragma unroll
        for (int o = 1; o < 16; o <<= 1)
#pragma unroll
          for (int r = 0; r < 4; ++r) pmax[r] = fmaxf(pmax[r], __shfl_xor(pmax[r], o, 64));
#pragma unroll
        for (int r = 0; r < 4; ++r) {
          float mnew = fmaxf(m_run[r], pmax[r]);
          float corr = __builtin_amdgcn_exp2f((m_run[r] - mnew) * L2E);
          m_run[r] = mnew;
          m2[r] = mnew * L2E;
          accl[r] *= corr;
#pragma unroll
          for (int df = 0; df < 4; ++df) acc[df][r] *= corr;
        }
      }

      const bool needC = (k0 + 63 > iw);
#pragma unroll
      for (int jf = 0; jf < 4; ++jf) {
        int jl = jf * 16 + (lane & 15);
        int j = k0 + jl;
        bool padj = padc[j - kbeg] != 0;
#pragma unroll
        for (int r = 0; r < 4; ++r) {
          float pe = __builtin_amdgcn_exp2f(__builtin_fmaf(sfr[jf][r], L2E, -m2[r]));
          bool ok = padj;
          if (needC) ok = ok && (j <= iw + (lane >> 4) * 4 + r);
          pe = ok ? pe : 0.f;
          int m = (lane >> 4) * 4 + r;
          *reinterpret_cast<bf16_t*>((char*)&Ps[w][0] + m * 128 + ((jl * 2) ^ ((m & 7) << 4))) =
              (bf16_t)pe;
        }
      }

      __builtin_amdgcn_s_setprio(1);
#pragma unroll
      for (int ks = 0; ks < 2; ++ks) {
        int mm = lane & 15;
        int inrow = (ks * 64 + (lane >> 4) * 16) ^ ((mm & 7) << 4);
        bf16x8 pa = *reinterpret_cast<const bf16x8*>((const char*)&Ps[w][0] + mm * 128 + inrow);
        accl = __builtin_amdgcn_mfma_f32_16x16x32_bf16(pa, ones, accl, 0, 0, 0);
#pragma unroll
        for (int df = 0; df < 4; ++df) {
          int d = df * 16 + (lane & 15);
          int vin = (ks * 64 + (lane >> 4) * 16) ^ ((d & 7) << 4);
          bf16x8 vf = *reinterpret_cast<const bf16x8*>(VsT + d * 128 + vin);
          acc[df] = __builtin_amdgcn_mfma_f32_16x16x32_bf16(pa, vf, acc[df], 0, 0, 0);
        }
      }
      __builtin_amdgcn_s_setprio(0);
    }
    __builtin_amdgcn_s_barrier();
  }
#undef STAGE

  if (nch == 1) {
    // single-chunk Q (Q<4): normalize and write Ob directly; row 0 owned by row-0 path
#pragma unroll
    for (int r = 0; r < 4; ++r) {
      float inv = 1.0f / accl[r];
      int row = w * 16 + (lane >> 4) * 4 + r;
#pragma unroll
      for (int df = 0; df < 4; ++df) {
        if (q0 + row != 0)
          Ob[(size_t)(q0 + row) * DIM + h * DH + df * 16 + (lane & 15)] =
              (bf16_t)(acc[df][r] * inv);
      }
    }
  } else {
    char* pb = part + (size_t)(h * PART_SLOTS + (slot - 4)) * PART_STRIDE;
    bf16_t* po = (bf16_t*)pb;
    float* pm = (float*)(pb + 16384);
    float* pl = (float*)(pb + 16896);
#pragma unroll
    for (int df = 0; df < 4; ++df)
#pragma unroll
      for (int r = 0; r < 4; ++r) {
        int row = w * 16 + (lane >> 4) * 4 + r;
        po[row * 64 + df * 16 + (lane & 15)] = (bf16_t)acc[df][r];
      }
    if ((lane & 15) == 0) {
#pragma unroll
      for (int r = 0; r < 4; ++r) {
        int row = w * 16 + (lane >> 4) * 4 + r;
        pm[row] = m2[r];       // log2 units
        pl[row] = accl[r];
      }
    }
  }
}

// ---- merge partials (Q>=4 only) -> Ob.  grid (12, 16): Q = bx+4 ----
__global__ __launch_bounds__(256) void k_merge(const char* __restrict__ part,
                                               bf16_t* __restrict__ Ob) {
  const int Q = blockIdx.x + 4, h = blockIdx.y;
  const int g = Q >> 2, nch = g + 1;
  const int cum = 2 * g * (g + 1) + (Q & 3) * nch - 4;
  const int t = threadIdx.x;
  const int row = t >> 1, half = t & 1;

  float acc[32];
#pragma unroll
  for (int e = 0; e < 32; ++e) acc[e] = 0.f;
  float M = -3e38f, L = 0.f;

  for (int c = 0; c < nch; ++c) {
    const char* pb = part + (size_t)(h * PART_SLOTS + cum + c) * PART_STRIDE;
    float mc = ((const float*)(pb + 16384))[row];
    float lc = ((const float*)(pb + 16896))[row];
    float Mn = fmaxf(M, mc);
    float sOld = __builtin_amdgcn_exp2f(M - Mn), sNew = __builtin_amdgcn_exp2f(mc - Mn);
    M = Mn;
    L = L * sOld + lc * sNew;
    const bf16_t* od = (const bf16_t*)pb + row * 64 + half * 32;
#pragma unroll
    for (int e4 = 0; e4 < 4; ++e4) {
      bf16x8 o8 = *reinterpret_cast<const bf16x8*>(od + e4 * 8);
#pragma unroll
      for (int e = 0; e < 8; ++e)
        acc[e4 * 8 + e] = acc[e4 * 8 + e] * sOld + (float)o8[e] * sNew;
    }
  }
  const float inv = 1.0f / L;
  bf16_t* dst = Ob + (size_t)(Q * 128 + row) * DIM + h * DH + half * 32;
#pragma unroll
  for (int e4 = 0; e4 < 4; ++e4) {
    bf16x8 r8o;
#pragma unroll
    for (int e = 0; e < 8; ++e) r8o[e] = (bf16_t)(acc[e4 * 8 + e] * inv);
    *reinterpret_cast<bf16x8*>(dst + e4 * 8) = r8o;
  }
}

// ---- host ----
extern "C" void kernel_launch(void* const* d_in, const int* in_sizes, int n_in,
                              void* d_out, int out_size, void* d_ws, size_t ws_size,
                              hipStream_t stream) {
  const float* x       = (const float*)d_in[0];
  const float* pos_sin = (const float*)d_in[1];
  const float* pos_cos = (const float*)d_in[2];
  const int*   mask    = (const int*)d_in[3];
  const float* ln_s    = (const float*)d_in[4];
  const float* ln_b    = (const float*)d_in[5];
  const float* w_qkv   = (const float*)d_in[6];
  const float* w_out   = (const float*)d_in[7];
  const float* b_out   = (const float*)d_in[8];
  float* out = (float*)d_out;

  if (ws_size < 33554432u) return;

  char* ws = (char*)d_ws;
  bf16_t* qkv  = (bf16_t*)(ws + 0);           // 12 MiB
  bf16_t* Vt   = (bf16_t*)(ws + 12582912);    //  4 MiB
  bf16_t* Ob   = (bf16_t*)(ws + 16777216);    //  4 MiB
  bf16_t* Wot  = (bf16_t*)(ws + 20971520);    //  2 MiB, alive whole run
  bf16_t* xn   = (bf16_t*)(ws + 23068672);    //  4 MiB, dead after QKV gemm
  bf16_t* Wqt  = (bf16_t*)(ws + 27262976);    //  6 MiB, dead after QKV gemm
  char*   part = ws + 23068672;               // 10.03 MiB (16*36*17408), overlays xn/Wqt

  k_ln_tc<<<NTOK + 768 + 256, 256, 0, stream>>>(x, ln_s, ln_b, xn, w_qkv, Wqt, w_out, Wot);
  k_gemm_bt<0><<<dim3(16, 24), 256, 0, stream>>>(xn, Wqt, qkv, nullptr, nullptr,
                                                 NTOK, QKVN, DIM);
  k_rope_vt<<<(NTOK - 1) + 512, 256, 0, stream>>>(qkv, pos_sin, pos_cos, Vt);
  k_attn_part<<<dim3(SLOTS_PER_HEAD + 1, NH), 512, 0, stream>>>(qkv, Vt, mask, part, Ob);
  k_merge<<<dim3(12, 16), 256, 0, stream>>>(part, Ob);
  k_gemm64<1><<<dim3(32, 8), 256, 0, stream>>>(Ob, Wot, nullptr, out, b_out,
                                               NTOK, DIM, DIM);
}

// Round 8
// 96.993 us; speedup vs baseline: 1.4232x; 1.0895x over previous
//
#include <hip/hip_runtime.h>
#include <hip/hip_bf16.h>
#include <stdint.h>

typedef __bf16 bf16_t;
typedef __bf16 bf16x8 __attribute__((ext_vector_type(8)));
typedef __bf16 bf16x4 __attribute__((ext_vector_type(4)));
typedef float  f32x4  __attribute__((ext_vector_type(4)));

#define DEV __device__ __forceinline__

static constexpr int NTOK = 2048;
static constexpr int DIM  = 1024;
static constexpr int NH   = 16;
static constexpr int DH   = 64;
static constexpr int QKVN = 3072;
static constexpr int SLOTS_PER_HEAD = 40;   // sum over Q=0..15 of ceil((Q+1)/4)
static constexpr int PART_SLOTS = 36;       // slots 4..39 go through part/merge
static constexpr int PART_STRIDE = 17408;   // 128x64 bf16 (16384) + m2[128] f32 + l[128] f32
static constexpr float L2E = 1.44269504f;

DEV void gload_lds16(const void* g, void* l) {
  __builtin_amdgcn_global_load_lds(
      (__attribute__((address_space(1))) void*)(g),
      (__attribute__((address_space(3))) void*)(l), 16, 0, 0);
}

DEV float bf2f(bf16_t b) { return (float)b; }

// ---- fused: LayerNorm (0..2047) + w_qkv T (2048..2815) + w_out T (2816..3071) ----
__global__ __launch_bounds__(256) void k_ln_tc(const float* __restrict__ x,
                                               const float* __restrict__ gamma,
                                               const float* __restrict__ beta,
                                               bf16_t* __restrict__ xn,
                                               const float* __restrict__ wsrc,
                                               bf16_t* __restrict__ wdst,
                                               const float* __restrict__ wosrc,
                                               bf16_t* __restrict__ wodst) {
  __shared__ float tile[64][65];
  __shared__ float red[8];
  int b = blockIdx.x;
  if (b < NTOK) {
    const int row = b;
    const int t = threadIdx.x;
    const float4* x4 = reinterpret_cast<const float4*>(x);
    float4 v = x4[(size_t)row * 256 + t];
    float s  = v.x + v.y + v.z + v.w;
    float s2 = v.x * v.x + v.y * v.y + v.z * v.z + v.w * v.w;
#pragma unroll
    for (int o = 1; o < 64; o <<= 1) {
      s  += __shfl_xor(s, o, 64);
      s2 += __shfl_xor(s2, o, 64);
    }
    const int w = t >> 6, lane = t & 63;
    if (lane == 0) { red[w] = s; red[4 + w] = s2; }
    __syncthreads();
    s  = red[0] + red[1] + red[2] + red[3];
    s2 = red[4] + red[5] + red[6] + red[7];
    const float mu  = s * (1.0f / 1024.0f);
    const float var = s2 * (1.0f / 1024.0f) - mu * mu;
    const float inv = rsqrtf(var + 1e-6f);
    const float4 g = reinterpret_cast<const float4*>(gamma)[t];
    const float4 bb = reinterpret_cast<const float4*>(beta)[t];
    bf16x4 o;
    o[0] = (bf16_t)((v.x - mu) * inv * g.x + bb.x);
    o[1] = (bf16_t)((v.y - mu) * inv * g.y + bb.y);
    o[2] = (bf16_t)((v.z - mu) * inv * g.z + bb.z);
    o[3] = (bf16_t)((v.w - mu) * inv * g.w + bb.w);
    *reinterpret_cast<bf16x4*>(xn + (size_t)row * DIM + t * 4) = o;
  } else if (b < NTOK + 768) {
    b -= NTOK;
    const int c0 = (b % 48) * 64;          // N = 3072
    const int r0 = (b / 48) * 64;          // M = 1024
    const int tx = threadIdx.x & 63;
    const int ty = threadIdx.x >> 6;
#pragma unroll
    for (int i = 0; i < 16; ++i) {
      int r = ty + i * 4;
      tile[r][tx] = wsrc[(size_t)(r0 + r) * 3072 + c0 + tx];
    }
    __syncthreads();
#pragma unroll
    for (int i = 0; i < 16; ++i) {
      int r = ty + i * 4;
      wdst[(size_t)(c0 + r) * 1024 + r0 + tx] = (bf16_t)tile[tx][r];
    }
  } else {
    b -= (NTOK + 768);
    const int c0 = (b & 15) * 64;          // N = 1024
    const int r0 = (b >> 4) * 64;          // M = 1024
    const int tx = threadIdx.x & 63;
    const int ty = threadIdx.x >> 6;
#pragma unroll
    for (int i = 0; i < 16; ++i) {
      int r = ty + i * 4;
      tile[r][tx] = wosrc[(size_t)(r0 + r) * 1024 + c0 + tx];
    }
    __syncthreads();
#pragma unroll
    for (int i = 0; i < 16; ++i) {
      int r = ty + i * 4;
      wodst[(size_t)(c0 + r) * 1024 + r0 + tx] = (bf16_t)tile[tx][r];
    }
  }
}

// ---- QKV GEMM 64x128 2-phase + fused RoPE/scale/V-transpose epilogue ----
// qkv[M=2048][3072] = xn * WqtT ; q cols roped+scaled(1/32), k cols roped, V cols -> Vt
__global__ __launch_bounds__(256) void k_gemm_qkv(const bf16_t* __restrict__ A,
                                                  const bf16_t* __restrict__ Bt,
                                                  bf16_t* __restrict__ qkv,
                                                  bf16_t* __restrict__ Vt,
                                                  const float* __restrict__ psin,
                                                  const float* __restrict__ pcos) {
  __shared__ alignas(16) bf16_t As[2][64 * 32];    // 2 x 4 KB
  __shared__ alignas(16) bf16_t Bs[2][128 * 32];   // 2 x 8 KB
  const int K = DIM;
  const int tid = threadIdx.x, lane = tid & 63, w = tid >> 6;
  const int bm = blockIdx.x * 64, bn = blockIdx.y * 128;
  const int wr = (w >> 1) * 32, wc = (w & 1) * 64;
  f32x4 acc[2][4];
#pragma unroll
  for (int i = 0; i < 2; ++i)
#pragma unroll
    for (int j = 0; j < 4; ++j) acc[i][j] = f32x4{0.f, 0.f, 0.f, 0.f};

  const int srow  = lane >> 2;
  const int scol8 = (lane & 3) * 8;

#define GSTAGEQ(KT, BUF)                                                              \
  {                                                                                   \
    _Pragma("unroll") for (int it = 0; it < 3; ++it) {                                \
      int s = w * 3 + it;                                                             \
      if (s < 4)                                                                      \
        gload_lds16(A + (size_t)(bm + s * 16 + srow) * K + (KT) + scol8,              \
                    (char*)As + (BUF) * 4096 + s * 1024 + lane * 16);                 \
      else                                                                            \
        gload_lds16(Bt + (size_t)(bn + (s - 4) * 16 + srow) * K + (KT) + scol8,       \
                    (char*)Bs + (BUF) * 8192 + (s - 4) * 1024 + lane * 16);           \
    }                                                                                 \
  }

  GSTAGEQ(0, 0)
  __syncthreads();
  int buf = 0;
  for (int kt = 0; kt < K; kt += 32, buf ^= 1) {
    if (kt + 32 < K) GSTAGEQ(kt + 32, buf ^ 1)
    bf16x8 af[2], bfr[4];
#pragma unroll
    for (int i = 0; i < 2; ++i) {
      int mrow = wr + i * 16 + (lane & 15);
      af[i] = *reinterpret_cast<const bf16x8*>((const char*)As + buf * 4096 + mrow * 64 +
                                               (lane >> 4) * 16);
    }
#pragma unroll
    for (int j = 0; j < 4; ++j) {
      int nrow = wc + j * 16 + (lane & 15);
      bfr[j] = *reinterpret_cast<const bf16x8*>((const char*)Bs + buf * 8192 + nrow * 64 +
                                                (lane >> 4) * 16);
    }
#pragma unroll
    for (int i = 0; i < 2; ++i)
#pragma unroll
      for (int j = 0; j < 4; ++j)
        acc[i][j] = __builtin_amdgcn_mfma_f32_16x16x32_bf16(af[i], bfr[j], acc[i][j], 0, 0, 0);
    __syncthreads();
  }
#undef GSTAGEQ

  if (bn >= 2048) {
    // V columns: write transposed into Vt[d][n] (8B per lane per (i,j))
#pragma unroll
    for (int i = 0; i < 2; ++i)
#pragma unroll
      for (int j = 0; j < 4; ++j) {
        int d = bn - 2048 + wc + j * 16 + (lane & 15);
        int n0v = bm + wr + i * 16 + (lane >> 4) * 4;
        bf16x4 v4;
#pragma unroll
        for (int r = 0; r < 4; ++r) v4[r] = (bf16_t)acc[i][j][r];
        *reinterpret_cast<bf16x4*>(Vt + (size_t)d * NTOK + n0v) = v4;
      }
  } else {
    // q/k columns: rope rows >=1 (pairs are adjacent lanes), q scaled by 1/32
#pragma unroll
    for (int i = 0; i < 2; ++i)
#pragma unroll
      for (int j = 0; j < 4; ++j) {
        int nn = bn + wc + j * 16 + (lane & 15);
        int tt = (nn & 63) >> 1;
        bool isq = nn < 1024;
#pragma unroll
        for (int r = 0; r < 4; ++r) {
          int mm = bm + wr + i * 16 + (lane >> 4) * 4 + r;
          float v = acc[i][j][r];
          float p = __shfl_xor(v, 1, 64);
          int pidx = (mm >= 1 ? mm - 1 : 0) * 32 + tt;
          float sn = psin[pidx], cs = pcos[pidx];
          float roped = (nn & 1) ? (v * cs + p * sn) : (v * cs - p * sn);
          if (mm < 1) roped = v;
          if (isq && mm >= 1) roped *= 0.03125f;
          qkv[(size_t)mm * QKVN + nn] = (bf16_t)roped;
        }
      }
  }
}

// ---- GEMM 64x128, 2-phase double-buffered (out projection, f32 out + bias) ----
template <int F32OUT>
__global__ __launch_bounds__(256) void k_gemm64(const bf16_t* __restrict__ A,
                                                const bf16_t* __restrict__ Bt,
                                                bf16_t* __restrict__ Cb,
                                                float* __restrict__ Cf,
                                                const float* __restrict__ bias,
                                                int M, int N, int K) {
  __shared__ alignas(16) bf16_t As[2][64 * 32];    // 2 x 4 KB
  __shared__ alignas(16) bf16_t Bs[2][128 * 32];   // 2 x 8 KB
  const int tid = threadIdx.x, lane = tid & 63, w = tid >> 6;
  const int bm = blockIdx.x * 64, bn = blockIdx.y * 128;
  const int wr = (w >> 1) * 32, wc = (w & 1) * 64;
  f32x4 acc[2][4];
#pragma unroll
  for (int i = 0; i < 2; ++i)
#pragma unroll
    for (int j = 0; j < 4; ++j) acc[i][j] = f32x4{0.f, 0.f, 0.f, 0.f};

  const int srow  = lane >> 2;
  const int scol8 = (lane & 3) * 8;

#define GSTAGE64(KT, BUF)                                                             \
  {                                                                                   \
    _Pragma("unroll") for (int it = 0; it < 3; ++it) {                                \
      int s = w * 3 + it;                                                             \
      if (s < 4)                                                                      \
        gload_lds16(A + (size_t)(bm + s * 16 + srow) * K + (KT) + scol8,              \
                    (char*)As + (BUF) * 4096 + s * 1024 + lane * 16);                 \
      else                                                                            \
        gload_lds16(Bt + (size_t)(bn + (s - 4) * 16 + srow) * K + (KT) + scol8,       \
                    (char*)Bs + (BUF) * 8192 + (s - 4) * 1024 + lane * 16);           \
    }                                                                                 \
  }

  GSTAGE64(0, 0)
  __syncthreads();
  int buf = 0;
  for (int kt = 0; kt < K; kt += 32, buf ^= 1) {
    if (kt + 32 < K) GSTAGE64(kt + 32, buf ^ 1)
    bf16x8 af[2], bfr[4];
#pragma unroll
    for (int i = 0; i < 2; ++i) {
      int mrow = wr + i * 16 + (lane & 15);
      af[i] = *reinterpret_cast<const bf16x8*>((const char*)As + buf * 4096 + mrow * 64 +
                                               (lane >> 4) * 16);
    }
#pragma unroll
    for (int j = 0; j < 4; ++j) {
      int nrow = wc + j * 16 + (lane & 15);
      bfr[j] = *reinterpret_cast<const bf16x8*>((const char*)Bs + buf * 8192 + nrow * 64 +
                                                (lane >> 4) * 16);
    }
#pragma unroll
    for (int i = 0; i < 2; ++i)
#pragma unroll
      for (int j = 0; j < 4; ++j)
        acc[i][j] = __builtin_amdgcn_mfma_f32_16x16x32_bf16(af[i], bfr[j], acc[i][j], 0, 0, 0);
    __syncthreads();
  }
#undef GSTAGE64

#pragma unroll
  for (int i = 0; i < 2; ++i)
#pragma unroll
    for (int j = 0; j < 4; ++j)
#pragma unroll
      for (int r = 0; r < 4; ++r) {
        int mm = bm + wr + i * 16 + (lane >> 4) * 4 + r;
        int nn = bn + wc + j * 16 + (lane & 15);
        float val = acc[i][j][r];
        if (F32OUT)
          Cf[(size_t)mm * N + nn] = val + bias[nn];
        else
          Cb[(size_t)mm * N + nn] = (bf16_t)val;
      }
}

// ---- flash attention partials (swapped-operand, in-lane softmax) + row-0 handler ----
// grid (41, 16), 512 thr. bx<40: causal slot (heavy-first); bx==40: non-causal row 0.
// Swapped QK^T: s = mfma(K,Q) -> lane holds P[key][q=lane&15]; K-fragment f covers
// keys ks*32 + g*8 + (f&1)*4 + r  (g = lane>>4) so P packs in-lane into PV's A-operand.
// LDS swizzle class phi(row) = (row&7) ^ (((row>>3)&3)<<1), applied stage+read.
__global__ __launch_bounds__(512) void k_attn_part(const bf16_t* __restrict__ qkv,
                                                   const bf16_t* __restrict__ Vt,
                                                   const int* __restrict__ mask,
                                                   char* __restrict__ part,
                                                   bf16_t* __restrict__ Ob) {
  __shared__ alignas(16) bf16_t Ks[2][64][64];   // 16 KB
  __shared__ alignas(16) bf16_t Vs[2][64][64];   // 16 KB
  __shared__ alignas(16) float padf[512];        //  2 KB

  const int h = blockIdx.y;

  if (blockIdx.x == SLOTS_PER_HEAD) {
    // ---------------- row 0: attends ALL 2048 keys, q un-roped/un-scaled ----------------
    float* qv   = padf;              // 64 f32
    float* sbuf = (float*)Ks;        // 2048 f32
    float* red  = (float*)Vs;        // 8 f32
    float* red2 = (float*)Vs + 64;   // 512 f32
    const int t = threadIdx.x, lane = t & 63, w8 = t >> 6;
    if (t < 64) qv[t] = (float)qkv[h * DH + t];
    __syncthreads();
    float sm[4];
    float lmax = -1e30f;
#pragma unroll
    for (int p = 0; p < 4; ++p) {
      int j = p * 512 + t;
      const bf16_t* kr = qkv + (size_t)j * QKVN + DIM + h * DH;
      float s = 0.f;
#pragma unroll
      for (int u = 0; u < 8; ++u) {
        bf16x8 kv8 = *reinterpret_cast<const bf16x8*>(kr + u * 8);
#pragma unroll
        for (int e = 0; e < 8; ++e) s += qv[u * 8 + e] * (float)kv8[e];
      }
      bool padj = (j == 0) || (mask[j - 1] != 0);
      s = padj ? s * 0.03125f : -1e30f;
      sm[p] = s;
      lmax = fmaxf(lmax, s);
    }
#pragma unroll
    for (int o = 1; o < 64; o <<= 1) lmax = fmaxf(lmax, __shfl_xor(lmax, o, 64));
    if (lane == 0) red[w8] = lmax;
    __syncthreads();
    float M = red[0];
#pragma unroll
    for (int i = 1; i < 8; ++i) M = fmaxf(M, red[i]);
    __syncthreads();
    float ls = 0.f;
#pragma unroll
    for (int p = 0; p < 4; ++p) {
      float pe = __expf(sm[p] - M);
      sbuf[p * 512 + t] = pe;
      ls += pe;
    }
#pragma unroll
    for (int o = 1; o < 64; o <<= 1) ls += __shfl_xor(ls, o, 64);
    if (lane == 0) red[w8] = ls;
    __syncthreads();
    float L = red[0];
#pragma unroll
    for (int i = 1; i < 8; ++i) L += red[i];

    const int d = t & 63, qr = t >> 6;
    const bf16_t* vr = Vt + ((size_t)h * DH + d) * NTOK + qr * 256;
    float a = 0.f;
#pragma unroll 8
    for (int u = 0; u < 32; ++u) {
      bf16x8 v8 = *reinterpret_cast<const bf16x8*>(vr + u * 8);
#pragma unroll
      for (int e = 0; e < 8; ++e) a += sbuf[qr * 256 + u * 8 + e] * (float)v8[e];
    }
    red2[qr * 64 + d] = a;
    __syncthreads();
    if (t < 64) {
      float o = 0.f;
#pragma unroll
      for (int i = 0; i < 8; ++i) o += red2[i * 64 + t];
      Ob[h * DH + t] = (bf16_t)(o / L);
    }
    return;
  }

  const int slot = (SLOTS_PER_HEAD - 1) - blockIdx.x;   // heavy slots first
  int gq;
  if (slot < 4) gq = 0; else if (slot < 12) gq = 1; else if (slot < 24) gq = 2; else gq = 3;
  const int tt = slot - 2 * gq * (gq + 1);
  const int Q = (gq << 2) + tt / (gq + 1);
  const int c2 = tt - (tt / (gq + 1)) * (gq + 1);
  const int q0 = Q * 128;
  const int kbeg = c2 * 512;
  const int kvlen = (Q + 1) * 128;
  const int klen = min(512, kvlen - kbeg);
  const int ntiles = klen >> 6;                 // 2,4,6,8
  const int nch = gq + 1;

  const int tid = threadIdx.x, lane = tid & 63, w = tid >> 6;
  const int g = lane >> 4;       // lane group: key sub-block / dim block
  const int c = lane & 15;       // q column (and A-row selector)

  for (int jr = tid; jr < klen; jr += 512) {
    int j = kbeg + jr;
    padf[jr] = (j == 0 || mask[j - 1] != 0) ? 1.f : 0.f;
  }

  const int iw = q0 + w * 16;
  bf16x8 qf[2];
  {
    const bf16_t* qp = qkv + (size_t)(iw + c) * QKVN + h * DH + g * 8;
    qf[0] = *reinterpret_cast<const bf16x8*>(qp);
    qf[1] = *reinterpret_cast<const bf16x8*>(qp + 32);
  }
  bf16x8 ones;
#pragma unroll
  for (int e = 0; e < 8; ++e) ones[e] = (bf16_t)1.0f;

  float m_run = -1e30f, m2 = -1e30f;
  f32x4 acc[4], accl;
#pragma unroll
  for (int df = 0; df < 4; ++df) acc[df] = f32x4{0.f, 0.f, 0.f, 0.f};
  accl = f32x4{0.f, 0.f, 0.f, 0.f};

  const int r8 = lane >> 3;

#define STAGE(KB, BUF)                                                                   \
  {                                                                                      \
    _Pragma("unroll") for (int i2 = 0; i2 < 2; ++i2) {                                   \
      int s = w * 2 + i2;                                                                \
      int sw = (lane & 7) ^ r8 ^ ((s & 3) << 1);                                         \
      if (s < 8) {                                                                       \
        int row = s * 8 + r8;                                                            \
        gload_lds16(qkv + (size_t)((KB) + row) * QKVN + DIM + h * DH + sw * 8,           \
                    (char*)Ks + (BUF)*8192 + s * 1024 + lane * 16);                      \
      } else {                                                                           \
        int row = (s - 8) * 8 + r8;                                                      \
        gload_lds16(Vt + ((size_t)h * DH + row) * NTOK + (KB) + sw * 8,                  \
                    (char*)Vs + (BUF)*8192 + (s - 8) * 1024 + lane * 16);                \
      }                                                                                  \
    }                                                                                    \
  }

  STAGE(kbeg, 0)

  for (int it = 0; it < ntiles; ++it) {
    const int buf = it & 1;
    if (it + 1 < ntiles) {
      STAGE(kbeg + (it + 1) * 64, buf ^ 1)
      asm volatile("s_waitcnt vmcnt(2)" ::: "memory");
    } else {
      asm volatile("s_waitcnt vmcnt(0)" ::: "memory");
    }
    __builtin_amdgcn_s_barrier();

    const int k0 = kbeg + it * 64;
    if (k0 <= iw + 15) {   // live tile for this wave
      const char* KsT = (const char*)Ks + buf * 8192;
      const char* VsT = (const char*)Vs + buf * 8192;

      // swapped QK^T: s = mfma(K, Q); fragment f covers keys ksf*32 + gp*8 + (f&1)*4 + r
      f32x4 sfr[4];
      __builtin_amdgcn_s_setprio(1);
#pragma unroll
      for (int f = 0; f < 4; ++f) {
        int key7 = ((f & 1) * 4) | (c & 3);
        int key = (f >> 1) * 32 + (c >> 2) * 8 + key7;
        int phi = key7 ^ (((c >> 2) & 3) << 1);
        f32x4 s = f32x4{0.f, 0.f, 0.f, 0.f};
#pragma unroll
        for (int kd = 0; kd < 2; ++kd) {
          bf16x8 kf = *reinterpret_cast<const bf16x8*>(
              KsT + key * 128 + (((kd * 4 + g) ^ phi) << 4));
          s = __builtin_amdgcn_mfma_f32_16x16x32_bf16(kf, qf[kd], s, 0, 0, 0);
        }
        sfr[f] = s;
      }
      __builtin_amdgcn_s_setprio(0);

      // in-lane row max (16 vals) + cross-group reduce (2 shfl)
      float pm = fmaxf(fmaxf(sfr[0][0], sfr[0][1]), fmaxf(sfr[0][2], sfr[0][3]));
#pragma unroll
      for (int f = 1; f < 4; ++f)
        pm = fmaxf(pm, fmaxf(fmaxf(sfr[f][0], sfr[f][1]), fmaxf(sfr[f][2], sfr[f][3])));
      pm = fmaxf(pm, __shfl_xor(pm, 16, 64));
      pm = fmaxf(pm, __shfl_xor(pm, 32, 64));

      if (!__all(pm <= m_run + 8.f)) {
        float mnew = fmaxf(m_run, pm);
        float corr = __builtin_amdgcn_exp2f((m_run - mnew) * L2E);
        m_run = mnew;
        m2 = mnew * L2E;
#pragma unroll
        for (int r = 0; r < 4; ++r) {
          float cr = __shfl(corr, g * 4 + r, 64);   // corr for q = g*4+r
          accl[r] *= cr;
#pragma unroll
          for (int df = 0; df < 4; ++df) acc[df][r] *= cr;
        }
      }

      const bool needC = (k0 + 63 > iw);
      const int qlane = iw + c;
      bf16x8 pa[2];
#pragma unroll
      for (int f = 0; f < 4; ++f) {
        int jb = (k0 - kbeg) + (f >> 1) * 32 + g * 8 + (f & 1) * 4;
        f32x4 pad4 = *reinterpret_cast<const f32x4*>(padf + jb);
#pragma unroll
        for (int r = 0; r < 4; ++r) {
          float pe = __builtin_amdgcn_exp2f(__builtin_fmaf(sfr[f][r], L2E, -m2)) * pad4[r];
          if (needC) pe = (kbeg + jb + r <= qlane) ? pe : 0.f;
          pa[f >> 1][(f & 1) * 4 + r] = (bf16_t)pe;
        }
      }

      __builtin_amdgcn_s_setprio(1);
#pragma unroll
      for (int ks = 0; ks < 2; ++ks) {
        accl = __builtin_amdgcn_mfma_f32_16x16x32_bf16(pa[ks], ones, accl, 0, 0, 0);
#pragma unroll
        for (int df = 0; df < 4; ++df) {
          int d = df * 16 + c;
          int phv = (d & 7) ^ (((d >> 3) & 3) << 1);
          bf16x8 vf = *reinterpret_cast<const bf16x8*>(
              VsT + d * 128 + (((ks * 4 + g) ^ phv) << 4));
          acc[df] = __builtin_amdgcn_mfma_f32_16x16x32_bf16(pa[ks], vf, acc[df], 0, 0, 0);
        }
      }
      __builtin_amdgcn_s_setprio(0);
    }
    __builtin_amdgcn_s_barrier();
  }
#undef STAGE

  if (nch == 1) {
    // single-chunk Q (Q<4): normalize and write Ob directly; row 0 owned by row-0 path
#pragma unroll
    for (int r = 0; r < 4; ++r) {
      float inv = 1.0f / accl[r];
      int row = w * 16 + g * 4 + r;
#pragma unroll
      for (int df = 0; df < 4; ++df) {
        if (q0 + row != 0)
          Ob[(size_t)(q0 + row) * DIM + h * DH + df * 16 + c] = (bf16_t)(acc[df][r] * inv);
      }
    }
  } else {
    char* pb = part + (size_t)(h * PART_SLOTS + (slot - 4)) * PART_STRIDE;
    bf16_t* po = (bf16_t*)pb;
    float* pmo = (float*)(pb + 16384);
    float* plo = (float*)(pb + 16896);
    float mq[4];
#pragma unroll
    for (int r = 0; r < 4; ++r) mq[r] = __shfl(m2, g * 4 + r, 64);   // m2 for q=g*4+r
#pragma unroll
    for (int df = 0; df < 4; ++df)
#pragma unroll
      for (int r = 0; r < 4; ++r) {
        int row = w * 16 + g * 4 + r;
        po[row * 64 + df * 16 + c] = (bf16_t)acc[df][r];
      }
    if (c == 0) {
#pragma unroll
      for (int r = 0; r < 4; ++r) {
        int row = w * 16 + g * 4 + r;
        pmo[row] = mq[r];      // log2 units
        plo[row] = accl[r];
      }
    }
  }
}

// ---- merge partials (Q>=4 only) -> Ob.  grid (12, 16): Q = bx+4 ----
__global__ __launch_bounds__(256) void k_merge(const char* __restrict__ part,
                                               bf16_t* __restrict__ Ob) {
  const int Q = blockIdx.x + 4, h = blockIdx.y;
  const int g = Q >> 2, nch = g + 1;
  const int cum = 2 * g * (g + 1) + (Q & 3) * nch - 4;
  const int t = threadIdx.x;
  const int row = t >> 1, half = t & 1;

  float acc[32];
#pragma unroll
  for (int e = 0; e < 32; ++e) acc[e] = 0.f;
  float M = -3e38f, L = 0.f;

  for (int c = 0; c < nch; ++c) {
    const char* pb = part + (size_t)(h * PART_SLOTS + cum + c) * PART_STRIDE;
    float mc = ((const float*)(pb + 16384))[row];
    float lc = ((const float*)(pb + 16896))[row];
    float Mn = fmaxf(M, mc);
    float sOld = __builtin_amdgcn_exp2f(M - Mn), sNew = __builtin_amdgcn_exp2f(mc - Mn);
    M = Mn;
    L = L * sOld + lc * sNew;
    const bf16_t* od = (const bf16_t*)pb + row * 64 + half * 32;
#pragma unroll
    for (int e4 = 0; e4 < 4; ++e4) {
      bf16x8 o8 = *reinterpret_cast<const bf16x8*>(od + e4 * 8);
#pragma unroll
      for (int e = 0; e < 8; ++e)
        acc[e4 * 8 + e] = acc[e4 * 8 + e] * sOld + (float)o8[e] * sNew;
    }
  }
  const float inv = 1.0f / L;
  bf16_t* dst = Ob + (size_t)(Q * 128 + row) * DIM + h * DH + half * 32;
#pragma unroll
  for (int e4 = 0; e4 < 4; ++e4) {
    bf16x8 r8o;
#pragma unroll
    for (int e = 0; e < 8; ++e) r8o[e] = (bf16_t)(acc[e4 * 8 + e] * inv);
    *reinterpret_cast<bf16x8*>(dst + e4 * 8) = r8o;
  }
}

// ---- host ----
extern "C" void kernel_launch(void* const* d_in, const int* in_sizes, int n_in,
                              void* d_out, int out_size, void* d_ws, size_t ws_size,
                              hipStream_t stream) {
  const float* x       = (const float*)d_in[0];
  const float* pos_sin = (const float*)d_in[1];
  const float* pos_cos = (const float*)d_in[2];
  const int*   mask    = (const int*)d_in[3];
  const float* ln_s    = (const float*)d_in[4];
  const float* ln_b    = (const float*)d_in[5];
  const float* w_qkv   = (const float*)d_in[6];
  const float* w_out   = (const float*)d_in[7];
  const float* b_out   = (const float*)d_in[8];
  float* out = (float*)d_out;

  if (ws_size < 33554432u) return;

  char* ws = (char*)d_ws;
  bf16_t* qkv  = (bf16_t*)(ws + 0);           // 12 MiB
  bf16_t* Vt   = (bf16_t*)(ws + 12582912);    //  4 MiB
  bf16_t* Ob   = (bf16_t*)(ws + 16777216);    //  4 MiB
  bf16_t* Wot  = (bf16_t*)(ws + 20971520);    //  2 MiB, alive whole run
  bf16_t* xn   = (bf16_t*)(ws + 23068672);    //  4 MiB, dead after QKV gemm
  bf16_t* Wqt  = (bf16_t*)(ws + 27262976);    //  6 MiB, dead after QKV gemm
  char*   part = ws + 23068672;               // 10.03 MiB (16*36*17408), overlays xn/Wqt

  k_ln_tc<<<NTOK + 768 + 256, 256, 0, stream>>>(x, ln_s, ln_b, xn, w_qkv, Wqt, w_out, Wot);
  k_gemm_qkv<<<dim3(32, 24), 256, 0, stream>>>(xn, Wqt, qkv, Vt, pos_sin, pos_cos);
  k_attn_part<<<dim3(SLOTS_PER_HEAD + 1, NH), 512, 0, stream>>>(qkv, Vt, mask, part, Ob);
  k_merge<<<dim3(12, 16), 256, 0, stream>>>(part, Ob);
  k_gemm64<1><<<dim3(32, 8), 256, 0, stream>>>(Ob, Wot, nullptr, out, b_out,
                                               NTOK, DIM, DIM);
}

// Round 11
// 96.824 us; speedup vs baseline: 1.4256x; 1.0017x over previous
//
#include <hip/hip_runtime.h>
#include <hip/hip_bf16.h>
#include <stdint.h>

typedef __bf16 bf16_t;
typedef __bf16 bf16x8 __attribute__((ext_vector_type(8)));
typedef __bf16 bf16x4 __attribute__((ext_vector_type(4)));
typedef float  f32x4  __attribute__((ext_vector_type(4)));

#define DEV __device__ __forceinline__

static constexpr int NTOK = 2048;
static constexpr int DIM  = 1024;
static constexpr int NH   = 16;
static constexpr int DH   = 64;
static constexpr int QKVN = 3072;
static constexpr int SLOTS_PER_HEAD = 40;   // sum over Q=0..15 of ceil((Q+1)/4)
static constexpr int PART_SLOTS = 36;       // slots 4..39 go through part/merge
static constexpr int PART_STRIDE = 17408;   // 128x64 bf16 (16384) + m2[128] f32 + l[128] f32
static constexpr float L2E = 1.44269504f;

DEV void gload_lds16(const void* g, void* l) {
  __builtin_amdgcn_global_load_lds(
      (__attribute__((address_space(1))) void*)(g),
      (__attribute__((address_space(3))) void*)(l), 16, 0, 0);
}

DEV float bf2f(bf16_t b) { return (float)b; }

// ---- fused: LayerNorm (0..2047) + w_qkv T (2048..2815) + w_out T (2816..3071) ----
__global__ __launch_bounds__(256) void k_ln_tc(const float* __restrict__ x,
                                               const float* __restrict__ gamma,
                                               const float* __restrict__ beta,
                                               bf16_t* __restrict__ xn,
                                               const float* __restrict__ wsrc,
                                               bf16_t* __restrict__ wdst,
                                               const float* __restrict__ wosrc,
                                               bf16_t* __restrict__ wodst) {
  __shared__ float tile[64][65];
  __shared__ float red[8];
  int b = blockIdx.x;
  if (b < NTOK) {
    const int row = b;
    const int t = threadIdx.x;
    const float4* x4 = reinterpret_cast<const float4*>(x);
    float4 v = x4[(size_t)row * 256 + t];
    float s  = v.x + v.y + v.z + v.w;
    float s2 = v.x * v.x + v.y * v.y + v.z * v.z + v.w * v.w;
#pragma unroll
    for (int o = 1; o < 64; o <<= 1) {
      s  += __shfl_xor(s, o, 64);
      s2 += __shfl_xor(s2, o, 64);
    }
    const int w = t >> 6, lane = t & 63;
    if (lane == 0) { red[w] = s; red[4 + w] = s2; }
    __syncthreads();
    s  = red[0] + red[1] + red[2] + red[3];
    s2 = red[4] + red[5] + red[6] + red[7];
    const float mu  = s * (1.0f / 1024.0f);
    const float var = s2 * (1.0f / 1024.0f) - mu * mu;
    const float inv = rsqrtf(var + 1e-6f);
    const float4 g = reinterpret_cast<const float4*>(gamma)[t];
    const float4 bb = reinterpret_cast<const float4*>(beta)[t];
    bf16x4 o;
    o[0] = (bf16_t)((v.x - mu) * inv * g.x + bb.x);
    o[1] = (bf16_t)((v.y - mu) * inv * g.y + bb.y);
    o[2] = (bf16_t)((v.z - mu) * inv * g.z + bb.z);
    o[3] = (bf16_t)((v.w - mu) * inv * g.w + bb.w);
    *reinterpret_cast<bf16x4*>(xn + (size_t)row * DIM + t * 4) = o;
  } else if (b < NTOK + 768) {
    b -= NTOK;
    const int c0 = (b % 48) * 64;          // N = 3072
    const int r0 = (b / 48) * 64;          // M = 1024
    const int tx = threadIdx.x & 63;
    const int ty = threadIdx.x >> 6;
#pragma unroll
    for (int i = 0; i < 16; ++i) {
      int r = ty + i * 4;
      tile[r][tx] = wsrc[(size_t)(r0 + r) * 3072 + c0 + tx];
    }
    __syncthreads();
#pragma unroll
    for (int i = 0; i < 16; ++i) {
      int r = ty + i * 4;
      wdst[(size_t)(c0 + r) * 1024 + r0 + tx] = (bf16_t)tile[tx][r];
    }
  } else {
    b -= (NTOK + 768);
    const int c0 = (b & 15) * 64;          // N = 1024
    const int r0 = (b >> 4) * 64;          // M = 1024
    const int tx = threadIdx.x & 63;
    const int ty = threadIdx.x >> 6;
#pragma unroll
    for (int i = 0; i < 16; ++i) {
      int r = ty + i * 4;
      tile[r][tx] = wosrc[(size_t)(r0 + r) * 1024 + c0 + tx];
    }
    __syncthreads();
#pragma unroll
    for (int i = 0; i < 16; ++i) {
      int r = ty + i * 4;
      wodst[(size_t)(c0 + r) * 1024 + r0 + tx] = (bf16_t)tile[tx][r];
    }
  }
}

// ---- QKV GEMM 64x128, counted-vmcnt 2-phase + fused RoPE/scale/V-transpose epilogue ----
// qkv[M=2048][3072] = xn * WqtT ; q cols roped+scaled(1/32), k cols roped, V cols -> Vt
__global__ __launch_bounds__(256) void k_gemm_qkv(const bf16_t* __restrict__ A,
                                                  const bf16_t* __restrict__ Bt,
                                                  bf16_t* __restrict__ qkv,
                                                  bf16_t* __restrict__ Vt,
                                                  const float* __restrict__ psin,
                                                  const float* __restrict__ pcos) {
  __shared__ alignas(16) bf16_t As[2][64 * 32];    // 2 x 4 KB
  __shared__ alignas(16) bf16_t Bs[2][128 * 32];   // 2 x 8 KB
  const int K = DIM;
  const int tid = threadIdx.x, lane = tid & 63, w = tid >> 6;
  const int bm = blockIdx.x * 64, bn = blockIdx.y * 128;
  const int wr = (w >> 1) * 32, wc = (w & 1) * 64;
  f32x4 acc[2][4];
#pragma unroll
  for (int i = 0; i < 2; ++i)
#pragma unroll
    for (int j = 0; j < 4; ++j) acc[i][j] = f32x4{0.f, 0.f, 0.f, 0.f};

  const int srow  = lane >> 2;
  const int scol8 = (lane & 3) * 8;

#define GSTAGEQ(KT, BUF)                                                              \
  {                                                                                   \
    _Pragma("unroll") for (int it = 0; it < 3; ++it) {                                \
      int s = w * 3 + it;                                                             \
      if (s < 4)                                                                      \
        gload_lds16(A + (size_t)(bm + s * 16 + srow) * K + (KT) + scol8,              \
                    (char*)As + (BUF) * 4096 + s * 1024 + lane * 16);                 \
      else                                                                            \
        gload_lds16(Bt + (size_t)(bn + (s - 4) * 16 + srow) * K + (KT) + scol8,       \
                    (char*)Bs + (BUF) * 8192 + (s - 4) * 1024 + lane * 16);           \
    }                                                                                 \
  }

  GSTAGEQ(0, 0)
  int buf = 0;
  for (int kt = 0; kt < K; kt += 32, buf ^= 1) {
    if (kt + 32 < K) {
      GSTAGEQ(kt + 32, buf ^ 1)
      asm volatile("s_waitcnt vmcnt(3)" ::: "memory");   // prev buffer's 3 landed; new 3 in flight
    } else {
      asm volatile("s_waitcnt vmcnt(0)" ::: "memory");
    }
    __builtin_amdgcn_s_barrier();
    bf16x8 af[2], bfr[4];
#pragma unroll
    for (int i = 0; i < 2; ++i) {
      int mrow = wr + i * 16 + (lane & 15);
      af[i] = *reinterpret_cast<const bf16x8*>((const char*)As + buf * 4096 + mrow * 64 +
                                               (lane >> 4) * 16);
    }
#pragma unroll
    for (int j = 0; j < 4; ++j) {
      int nrow = wc + j * 16 + (lane & 15);
      bfr[j] = *reinterpret_cast<const bf16x8*>((const char*)Bs + buf * 8192 + nrow * 64 +
                                                (lane >> 4) * 16);
    }
#pragma unroll
    for (int i = 0; i < 2; ++i)
#pragma unroll
      for (int j = 0; j < 4; ++j)
        acc[i][j] = __builtin_amdgcn_mfma_f32_16x16x32_bf16(af[i], bfr[j], acc[i][j], 0, 0, 0);
    __builtin_amdgcn_s_barrier();   // all waves done reading buf before it is restaged
  }
#undef GSTAGEQ

  if (bn >= 2048) {
    // V columns: write transposed into Vt[d][n] (8B per lane per (i,j))
#pragma unroll
    for (int i = 0; i < 2; ++i)
#pragma unroll
      for (int j = 0; j < 4; ++j) {
        int d = bn - 2048 + wc + j * 16 + (lane & 15);
        int n0v = bm + wr + i * 16 + (lane >> 4) * 4;
        bf16x4 v4;
#pragma unroll
        for (int r = 0; r < 4; ++r) v4[r] = (bf16_t)acc[i][j][r];
        *reinterpret_cast<bf16x4*>(Vt + (size_t)d * NTOK + n0v) = v4;
      }
  } else {
    // q/k columns: rope rows >=1 (pairs are adjacent lanes), q scaled by 1/32
#pragma unroll
    for (int i = 0; i < 2; ++i)
#pragma unroll
      for (int j = 0; j < 4; ++j) {
        int nn = bn + wc + j * 16 + (lane & 15);
        int tt = (nn & 63) >> 1;
        bool isq = nn < 1024;
#pragma unroll
        for (int r = 0; r < 4; ++r) {
          int mm = bm + wr + i * 16 + (lane >> 4) * 4 + r;
          float v = acc[i][j][r];
          float p = __shfl_xor(v, 1, 64);
          int pidx = (mm >= 1 ? mm - 1 : 0) * 32 + tt;
          float sn = psin[pidx], cs = pcos[pidx];
          float roped = (nn & 1) ? (v * cs + p * sn) : (v * cs - p * sn);
          if (mm < 1) roped = v;
          if (isq && mm >= 1) roped *= 0.03125f;
          qkv[(size_t)mm * QKVN + nn] = (bf16_t)roped;
        }
      }
  }
}

// ---- GEMM 64x128, counted-vmcnt 2-phase (out projection, f32 out + bias) ----
template <int F32OUT>
__global__ __launch_bounds__(256) void k_gemm64(const bf16_t* __restrict__ A,
                                                const bf16_t* __restrict__ Bt,
                                                bf16_t* __restrict__ Cb,
                                                float* __restrict__ Cf,
                                                const float* __restrict__ bias,
                                                int M, int N, int K) {
  __shared__ alignas(16) bf16_t As[2][64 * 32];    // 2 x 4 KB
  __shared__ alignas(16) bf16_t Bs[2][128 * 32];   // 2 x 8 KB
  const int tid = threadIdx.x, lane = tid & 63, w = tid >> 6;
  const int bm = blockIdx.x * 64, bn = blockIdx.y * 128;
  const int wr = (w >> 1) * 32, wc = (w & 1) * 64;
  f32x4 acc[2][4];
#pragma unroll
  for (int i = 0; i < 2; ++i)
#pragma unroll
    for (int j = 0; j < 4; ++j) acc[i][j] = f32x4{0.f, 0.f, 0.f, 0.f};

  const int srow  = lane >> 2;
  const int scol8 = (lane & 3) * 8;

#define GSTAGE64(KT, BUF)                                                             \
  {                                                                                   \
    _Pragma("unroll") for (int it = 0; it < 3; ++it) {                                \
      int s = w * 3 + it;                                                             \
      if (s < 4)                                                                      \
        gload_lds16(A + (size_t)(bm + s * 16 + srow) * K + (KT) + scol8,              \
                    (char*)As + (BUF) * 4096 + s * 1024 + lane * 16);                 \
      else                                                                            \
        gload_lds16(Bt + (size_t)(bn + (s - 4) * 16 + srow) * K + (KT) + scol8,       \
                    (char*)Bs + (BUF) * 8192 + (s - 4) * 1024 + lane * 16);           \
    }                                                                                 \
  }

  GSTAGE64(0, 0)
  int buf = 0;
  for (int kt = 0; kt < K; kt += 32, buf ^= 1) {
    if (kt + 32 < K) {
      GSTAGE64(kt + 32, buf ^ 1)
      asm volatile("s_waitcnt vmcnt(3)" ::: "memory");
    } else {
      asm volatile("s_waitcnt vmcnt(0)" ::: "memory");
    }
    __builtin_amdgcn_s_barrier();
    bf16x8 af[2], bfr[4];
#pragma unroll
    for (int i = 0; i < 2; ++i) {
      int mrow = wr + i * 16 + (lane & 15);
      af[i] = *reinterpret_cast<const bf16x8*>((const char*)As + buf * 4096 + mrow * 64 +
                                               (lane >> 4) * 16);
    }
#pragma unroll
    for (int j = 0; j < 4; ++j) {
      int nrow = wc + j * 16 + (lane & 15);
      bfr[j] = *reinterpret_cast<const bf16x8*>((const char*)Bs + buf * 8192 + nrow * 64 +
                                                (lane >> 4) * 16);
    }
#pragma unroll
    for (int i = 0; i < 2; ++i)
#pragma unroll
      for (int j = 0; j < 4; ++j)
        acc[i][j] = __builtin_amdgcn_mfma_f32_16x16x32_bf16(af[i], bfr[j], acc[i][j], 0, 0, 0);
    __builtin_amdgcn_s_barrier();
  }
#undef GSTAGE64

#pragma unroll
  for (int i = 0; i < 2; ++i)
#pragma unroll
    for (int j = 0; j < 4; ++j)
#pragma unroll
      for (int r = 0; r < 4; ++r) {
        int mm = bm + wr + i * 16 + (lane >> 4) * 4 + r;
        int nn = bn + wc + j * 16 + (lane & 15);
        float val = acc[i][j][r];
        if (F32OUT)
          Cf[(size_t)mm * N + nn] = val + bias[nn];
        else
          Cb[(size_t)mm * N + nn] = (bf16_t)val;
      }
}

// ---- flash attention partials (swapped-operand, in-lane softmax) + row-0 handler ----
// grid (41, 16), 512 thr. bx<40: causal slot (heavy-first); bx==40: non-causal row 0.
__global__ __launch_bounds__(512) void k_attn_part(const bf16_t* __restrict__ qkv,
                                                   const bf16_t* __restrict__ Vt,
                                                   const int* __restrict__ mask,
                                                   char* __restrict__ part,
                                                   bf16_t* __restrict__ Ob) {
  __shared__ alignas(16) bf16_t Ks[2][64][64];   // 16 KB
  __shared__ alignas(16) bf16_t Vs[2][64][64];   // 16 KB
  __shared__ alignas(16) float padf[512];        //  2 KB

  const int h = blockIdx.y;

  if (blockIdx.x == SLOTS_PER_HEAD) {
    // ---------------- row 0: attends ALL 2048 keys, q un-roped/un-scaled ----------------
    float* qv   = padf;              // 64 f32
    float* sbuf = (float*)Ks;        // 2048 f32
    float* red  = (float*)Vs;        // 8 f32
    float* red2 = (float*)Vs + 64;   // 512 f32
    const int t = threadIdx.x, lane = t & 63, w8 = t >> 6;
    if (t < 64) qv[t] = (float)qkv[h * DH + t];
    __syncthreads();
    float sm[4];
    float lmax = -1e30f;
#pragma unroll
    for (int p = 0; p < 4; ++p) {
      int j = p * 512 + t;
      const bf16_t* kr = qkv + (size_t)j * QKVN + DIM + h * DH;
      float s = 0.f;
#pragma unroll
      for (int u = 0; u < 8; ++u) {
        bf16x8 kv8 = *reinterpret_cast<const bf16x8*>(kr + u * 8);
#pragma unroll
        for (int e = 0; e < 8; ++e) s += qv[u * 8 + e] * (float)kv8[e];
      }
      bool padj = (j == 0) || (mask[j - 1] != 0);
      s = padj ? s * 0.03125f : -1e30f;
      sm[p] = s;
      lmax = fmaxf(lmax, s);
    }
#pragma unroll
    for (int o = 1; o < 64; o <<= 1) lmax = fmaxf(lmax, __shfl_xor(lmax, o, 64));
    if (lane == 0) red[w8] = lmax;
    __syncthreads();
    float M = red[0];
#pragma unroll
    for (int i = 1; i < 8; ++i) M = fmaxf(M, red[i]);
    __syncthreads();
    float ls = 0.f;
#pragma unroll
    for (int p = 0; p < 4; ++p) {
      float pe = __expf(sm[p] - M);
      sbuf[p * 512 + t] = pe;
      ls += pe;
    }
#pragma unroll
    for (int o = 1; o < 64; o <<= 1) ls += __shfl_xor(ls, o, 64);
    if (lane == 0) red[w8] = ls;
    __syncthreads();
    float L = red[0];
#pragma unroll
    for (int i = 1; i < 8; ++i) L += red[i];

    const int d = t & 63, qr = t >> 6;
    const bf16_t* vr = Vt + ((size_t)h * DH + d) * NTOK + qr * 256;
    float a = 0.f;
#pragma unroll 8
    for (int u = 0; u < 32; ++u) {
      bf16x8 v8 = *reinterpret_cast<const bf16x8*>(vr + u * 8);
#pragma unroll
      for (int e = 0; e < 8; ++e) a += sbuf[qr * 256 + u * 8 + e] * (float)v8[e];
    }
    red2[qr * 64 + d] = a;
    __syncthreads();
    if (t < 64) {
      float o = 0.f;
#pragma unroll
      for (int i = 0; i < 8; ++i) o += red2[i * 64 + t];
      Ob[h * DH + t] = (bf16_t)(o / L);
    }
    return;
  }

  const int slot = (SLOTS_PER_HEAD - 1) - blockIdx.x;   // heavy slots first
  int gq;
  if (slot < 4) gq = 0; else if (slot < 12) gq = 1; else if (slot < 24) gq = 2; else gq = 3;
  const int tt = slot - 2 * gq * (gq + 1);
  const int Q = (gq << 2) + tt / (gq + 1);
  const int c2 = tt - (tt / (gq + 1)) * (gq + 1);
  const int q0 = Q * 128;
  const int kbeg = c2 * 512;
  const int kvlen = (Q + 1) * 128;
  const int klen = min(512, kvlen - kbeg);
  const int ntiles = klen >> 6;                 // 2,4,6,8
  const int nch = gq + 1;

  const int tid = threadIdx.x, lane = tid & 63, w = tid >> 6;
  const int g = lane >> 4;       // lane group
  const int c = lane & 15;       // q column

  for (int jr = tid; jr < klen; jr += 512) {
    int j = kbeg + jr;
    padf[jr] = (j == 0 || mask[j - 1] != 0) ? 1.f : 0.f;
  }

  const int iw = q0 + w * 16;
  bf16x8 qf[2];
  {
    const bf16_t* qp = qkv + (size_t)(iw + c) * QKVN + h * DH + g * 8;
    qf[0] = *reinterpret_cast<const bf16x8*>(qp);
    qf[1] = *reinterpret_cast<const bf16x8*>(qp + 32);
  }
  bf16x8 ones;
#pragma unroll
  for (int e = 0; e < 8; ++e) ones[e] = (bf16_t)1.0f;

  float m_run = -1e30f, m2 = -1e30f;
  f32x4 acc[4], accl;
#pragma unroll
  for (int df = 0; df < 4; ++df) acc[df] = f32x4{0.f, 0.f, 0.f, 0.f};
  accl = f32x4{0.f, 0.f, 0.f, 0.f};

  const int r8 = lane >> 3;

#define STAGE(KB, BUF)                                                                   \
  {                                                                                      \
    _Pragma("unroll") for (int i2 = 0; i2 < 2; ++i2) {                                   \
      int s = w * 2 + i2;                                                                \
      int sw = (lane & 7) ^ r8 ^ ((s & 3) << 1);                                         \
      if (s < 8) {                                                                       \
        int row = s * 8 + r8;                                                            \
        gload_lds16(qkv + (size_t)((KB) + row) * QKVN + DIM + h * DH + sw * 8,           \
                    (char*)Ks + (BUF)*8192 + s * 1024 + lane * 16);                      \
      } else {                                                                           \
        int row = (s - 8) * 8 + r8;                                                      \
        gload_lds16(Vt + ((size_t)h * DH + row) * NTOK + (KB) + sw * 8,                  \
                    (char*)Vs + (BUF)*8192 + (s - 8) * 1024 + lane * 16);                \
      }                                                                                  \
    }                                                                                    \
  }

  STAGE(kbeg, 0)

  for (int it = 0; it < ntiles; ++it) {
    const int buf = it & 1;
    if (it + 1 < ntiles) {
      STAGE(kbeg + (it + 1) * 64, buf ^ 1)
      asm volatile("s_waitcnt vmcnt(2)" ::: "memory");
    } else {
      asm volatile("s_waitcnt vmcnt(0)" ::: "memory");
    }
    __builtin_amdgcn_s_barrier();

    const int k0 = kbeg + it * 64;
    if (k0 <= iw + 15) {
      const char* KsT = (const char*)Ks + buf * 8192;
      const char* VsT = (const char*)Vs + buf * 8192;

      f32x4 sfr[4];
      __builtin_amdgcn_s_setprio(1);
#pragma unroll
      for (int f = 0; f < 4; ++f) {
        int key7 = ((f & 1) * 4) | (c & 3);
        int key = (f >> 1) * 32 + (c >> 2) * 8 + key7;
        int phi = key7 ^ (((c >> 2) & 3) << 1);
        f32x4 s = f32x4{0.f, 0.f, 0.f, 0.f};
#pragma unroll
        for (int kd = 0; kd < 2; ++kd) {
          bf16x8 kf = *reinterpret_cast<const bf16x8*>(
              KsT + key * 128 + (((kd * 4 + g) ^ phi) << 4));
          s = __builtin_amdgcn_mfma_f32_16x16x32_bf16(kf, qf[kd], s, 0, 0, 0);
        }
        sfr[f] = s;
      }
      __builtin_amdgcn_s_setprio(0);

      float pm = fmaxf(fmaxf(sfr[0][0], sfr[0][1]), fmaxf(sfr[0][2], sfr[0][3]));
#pragma unroll
      for (int f = 1; f < 4; ++f)
        pm = fmaxf(pm, fmaxf(fmaxf(sfr[f][0], sfr[f][1]), fmaxf(sfr[f][2], sfr[f][3])));
      pm = fmaxf(pm, __shfl_xor(pm, 16, 64));
      pm = fmaxf(pm, __shfl_xor(pm, 32, 64));

      if (!__all(pm <= m_run + 8.f)) {
        float mnew = fmaxf(m_run, pm);
        float corr = __builtin_amdgcn_exp2f((m_run - mnew) * L2E);
        m_run = mnew;
        m2 = mnew * L2E;
#pragma unroll
        for (int r = 0; r < 4; ++r) {
          float cr = __shfl(corr, g * 4 + r, 64);
          accl[r] *= cr;
#pragma unroll
          for (int df = 0; df < 4; ++df) acc[df][r] *= cr;
        }
      }

      const bool needC = (k0 + 63 > iw);
      const int qlane = iw + c;
      bf16x8 pa[2];
#pragma unroll
      for (int f = 0; f < 4; ++f) {
        int jb = (k0 - kbeg) + (f >> 1) * 32 + g * 8 + (f & 1) * 4;
        f32x4 pad4 = *reinterpret_cast<const f32x4*>(padf + jb);
#pragma unroll
        for (int r = 0; r < 4; ++r) {
          float pe = __builtin_amdgcn_exp2f(__builtin_fmaf(sfr[f][r], L2E, -m2)) * pad4[r];
          if (needC) pe = (kbeg + jb + r <= qlane) ? pe : 0.f;
          pa[f >> 1][(f & 1) * 4 + r] = (bf16_t)pe;
        }
      }

      __builtin_amdgcn_s_setprio(1);
#pragma unroll
      for (int ks = 0; ks < 2; ++ks) {
        accl = __builtin_amdgcn_mfma_f32_16x16x32_bf16(pa[ks], ones, accl, 0, 0, 0);
#pragma unroll
        for (int df = 0; df < 4; ++df) {
          int d = df * 16 + c;
          int phv = (d & 7) ^ (((d >> 3) & 3) << 1);
          bf16x8 vf = *reinterpret_cast<const bf16x8*>(
              VsT + d * 128 + (((ks * 4 + g) ^ phv) << 4));
          acc[df] = __builtin_amdgcn_mfma_f32_16x16x32_bf16(pa[ks], vf, acc[df], 0, 0, 0);
        }
      }
      __builtin_amdgcn_s_setprio(0);
    }
    __builtin_amdgcn_s_barrier();
  }
#undef STAGE

  if (nch == 1) {
    // single-chunk Q (Q<4): normalize and write Ob directly; row 0 owned by row-0 path
#pragma unroll
    for (int r = 0; r < 4; ++r) {
      float inv = 1.0f / accl[r];
      int row = w * 16 + g * 4 + r;
#pragma unroll
      for (int df = 0; df < 4; ++df) {
        if (q0 + row != 0)
          Ob[(size_t)(q0 + row) * DIM + h * DH + df * 16 + c] = (bf16_t)(acc[df][r] * inv);
      }
    }
    return;
  }

  // write unnormalized partial (merged by separate k_merge kernel)
  char* pb = part + (size_t)(h * PART_SLOTS + (slot - 4)) * PART_STRIDE;
  bf16_t* po = (bf16_t*)pb;
  float* pmo = (float*)(pb + 16384);
  float* plo = (float*)(pb + 16896);
  float mq[4];
#pragma unroll
  for (int r = 0; r < 4; ++r) mq[r] = __shfl(m2, g * 4 + r, 64);
#pragma unroll
  for (int df = 0; df < 4; ++df)
#pragma unroll
    for (int r = 0; r < 4; ++r) {
      int row = w * 16 + g * 4 + r;
      po[row * 64 + df * 16 + c] = (bf16_t)acc[df][r];
    }
  if (c == 0) {
#pragma unroll
    for (int r = 0; r < 4; ++r) {
      int row = w * 16 + g * 4 + r;
      pmo[row] = mq[r];      // log2 units
      plo[row] = accl[r];
    }
  }
}

// ---- merge partials (Q>=4 only) -> Ob.  grid (12, 16): Q = bx+4 ----
__global__ __launch_bounds__(256) void k_merge(const char* __restrict__ part,
                                               bf16_t* __restrict__ Ob) {
  const int Q = blockIdx.x + 4, h = blockIdx.y;
  const int g = Q >> 2, nch = g + 1;
  const int cum = 2 * g * (g + 1) + (Q & 3) * nch - 4;
  const int t = threadIdx.x;
  const int row = t >> 1, half = t & 1;

  float acc[32];
#pragma unroll
  for (int e = 0; e < 32; ++e) acc[e] = 0.f;
  float M = -3e38f, L = 0.f;

  for (int c = 0; c < nch; ++c) {
    const char* pb = part + (size_t)(h * PART_SLOTS + cum + c) * PART_STRIDE;
    float mc = ((const float*)(pb + 16384))[row];
    float lc = ((const float*)(pb + 16896))[row];
    float Mn = fmaxf(M, mc);
    float sOld = __builtin_amdgcn_exp2f(M - Mn), sNew = __builtin_amdgcn_exp2f(mc - Mn);
    M = Mn;
    L = L * sOld + lc * sNew;
    const bf16_t* od = (const bf16_t*)pb + row * 64 + half * 32;
#pragma unroll
    for (int e4 = 0; e4 < 4; ++e4) {
      bf16x8 o8 = *reinterpret_cast<const bf16x8*>(od + e4 * 8);
#pragma unroll
      for (int e = 0; e < 8; ++e)
        acc[e4 * 8 + e] = acc[e4 * 8 + e] * sOld + (float)o8[e] * sNew;
    }
  }
  const float inv = 1.0f / L;
  bf16_t* dst = Ob + (size_t)(Q * 128 + row) * DIM + h * DH + half * 32;
#pragma unroll
  for (int e4 = 0; e4 < 4; ++e4) {
    bf16x8 r8o;
#pragma unroll
    for (int e = 0; e < 8; ++e) r8o[e] = (bf16_t)(acc[e4 * 8 + e] * inv);
    *reinterpret_cast<bf16x8*>(dst + e4 * 8) = r8o;
  }
}

// ---- host ----
extern "C" void kernel_launch(void* const* d_in, const int* in_sizes, int n_in,
                              void* d_out, int out_size, void* d_ws, size_t ws_size,
                              hipStream_t stream) {
  const float* x       = (const float*)d_in[0];
  const float* pos_sin = (const float*)d_in[1];
  const float* pos_cos = (const float*)d_in[2];
  const int*   mask    = (const int*)d_in[3];
  const float* ln_s    = (const float*)d_in[4];
  const float* ln_b    = (const float*)d_in[5];
  const float* w_qkv   = (const float*)d_in[6];
  const float* w_out   = (const float*)d_in[7];
  const float* b_out   = (const float*)d_in[8];
  float* out = (float*)d_out;

  if (ws_size < 33554432u) return;

  char* ws = (char*)d_ws;
  bf16_t* qkv  = (bf16_t*)(ws + 0);           // 12 MiB
  bf16_t* Vt   = (bf16_t*)(ws + 12582912);    //  4 MiB
  bf16_t* Ob   = (bf16_t*)(ws + 16777216);    //  4 MiB
  bf16_t* Wot  = (bf16_t*)(ws + 20971520);    //  2 MiB, alive whole run
  bf16_t* xn   = (bf16_t*)(ws + 23068672);    //  4 MiB, dead after QKV gemm
  bf16_t* Wqt  = (bf16_t*)(ws + 27262976);    //  6 MiB, dead after QKV gemm
  char*   part = ws + 23068672;               // 10.03 MiB (16*36*17408), overlays xn/Wqt

  k_ln_tc<<<NTOK + 768 + 256, 256, 0, stream>>>(x, ln_s, ln_b, xn, w_qkv, Wqt, w_out, Wot);
  k_gemm_qkv<<<dim3(32, 24), 256, 0, stream>>>(xn, Wqt, qkv, Vt, pos_sin, pos_cos);
  k_attn_part<<<dim3(SLOTS_PER_HEAD + 1, NH), 512, 0, stream>>>(qkv, Vt, mask, part, Ob);
  k_merge<<<dim3(12, 16), 256, 0, stream>>>(part, Ob);
  k_gemm64<1><<<dim3(32, 8), 256, 0, stream>>>(Ob, Wot, nullptr, out, b_out,
                                               NTOK, DIM, DIM);
}